// Round 11
// baseline (682.093 us; speedup 1.0000x reference)
//
#include <hip/hip_runtime.h>
#include <math.h>

#define L_SEQ 4000
#define DM 768
#define DI 1536
#define DS 16
#define DTRK 48
#define NCH 50
#define LC 80
#define NBL 8000

typedef __attribute__((ext_vector_type(8))) short short8;
typedef __attribute__((ext_vector_type(8))) unsigned short ushort8;
typedef __attribute__((ext_vector_type(4))) unsigned short ushort4v;
typedef __attribute__((ext_vector_type(4))) float floatx4;
typedef __attribute__((ext_vector_type(2))) float float2v;

__device__ __forceinline__ float silu_f(float x) { return x / (1.f + __expf(-x)); }
// fast softplus: log1pf -> __logf(1+e); e>0 so no cancellation; when 1+e rounds
// to 1 the true value <= 6e-8, invisible in bf16 output.
__device__ __forceinline__ float softplus_f(float x) {
  return fmaxf(x, 0.f) + __logf(1.f + __expf(-fabsf(x)));
}
__device__ __forceinline__ int map_t(int branch, int t) {
  if (branch == 0) return t;
  if (branch == 1) return L_SEQ - 1 - t;
  return (t % 5) * 800 + t / 5;
}
__device__ __forceinline__ unsigned short f2bf(float f) {
  unsigned int u = __float_as_uint(f);
  u = (u + 0x7fffu + ((u >> 16) & 1u)) >> 16;
  return (unsigned short)u;
}
__device__ __forceinline__ float bf2f(unsigned short u) {
  return __uint_as_float(((unsigned int)u) << 16);
}
__device__ __forceinline__ void glds16(const void* g, void* l) {
  __builtin_amdgcn_global_load_lds((const __attribute__((address_space(1))) void*)g,
                                   (__attribute__((address_space(3))) void*)l, 16, 0, 0);
}
// packed power ladder, TREE form (dep depth 4 vs 8 of the serial ladder):
// dc2[i] = {E^(2i+1), E^(2i+2)} for i=0..7, built from E2/E4/E8 squarings.
__device__ __forceinline__ void pow_ladder2(float E1, float2v* dc2) {
  float E2 = E1 * E1;
  float E4 = E2 * E2;
  float E8 = E4 * E4;
  float2v v4 = {E4, E4}, v8 = {E8, E8};
  dc2[0] = (float2v){E1, E2};
  dc2[1] = dc2[0] * (float2v){E2, E2};  // E3,E4
  dc2[2] = dc2[0] * v4;                 // E5,E6
  dc2[3] = dc2[1] * v4;                 // E7,E8
  dc2[4] = dc2[0] * v8;                 // E9,E10
  dc2[5] = dc2[1] * v8;                 // E11,E12
  dc2[6] = dc2[2] * v8;                 // E13,E14
  dc2[7] = dc2[3] * v8;                 // E15,E16
}

// ---------------- merged cast fp32 -> bf16 for all 5 weight/input arrays ----------------
__device__ __forceinline__ void cast_seg(const float* __restrict__ src,
                                         unsigned short* __restrict__ dst,
                                         int blk, int n) {
  int i = (blk * 256 + (int)threadIdx.x) * 8;
  if (i >= n) return;
  float4 v0 = *(const float4*)&src[i];
  float4 v1 = *(const float4*)&src[i + 4];
  ushort8 r;
  r[0] = f2bf(v0.x); r[1] = f2bf(v0.y); r[2] = f2bf(v0.z); r[3] = f2bf(v0.w);
  r[4] = f2bf(v1.x); r[5] = f2bf(v1.y); r[6] = f2bf(v1.z); r[7] = f2bf(v1.w);
  *(ushort8*)&dst[i] = r;
}
__global__ __launch_bounds__(256) void k_cast5(const float* s0, unsigned short* d0,
                                               const float* s1, unsigned short* d1,
                                               const float* s2, unsigned short* d2,
                                               const float* s3, unsigned short* d3,
                                               const float* s4, unsigned short* d4) {
  int blk = blockIdx.x;
  if (blk < 3000)      cast_seg(s0, d0, blk,        6144000);
  else if (blk < 4152) cast_seg(s1, d1, blk - 3000, 2359296);
  else if (blk < 4728) cast_seg(s2, d2, blk - 4152, 1179648);
  else if (blk < 4836) cast_seg(s3, d3, blk - 4728, 221184);
  else                 cast_seg(s4, d4, blk - 4836, 368640);
}

// ---------------- MFMA GEMM (bt): C[m][n] = sum_k A[m][(k%KA)]*B[n][k] ----
// 1D grid, XCD-chunked bijective swizzle (T1/m204). BMAJ=1: B is the in-place
// dT buffer; row bases via per-branch inverse time maps.
// T2 LDS k-slot XOR swizzle (both-sides form, rule #21): logical slot l of row
// r at physical slot l ^ ((r>>1)&3); glds source pre-permuted by the same
// involution; fragment reads apply it too. Bank conflicts measured 0 (r10).
// T3-minimum 2-phase double-buffer: stage tile k+1 into buf^1 BEFORE the
// ds_read+MFMA of tile k; ONE barrier per K-step. The barrier's implicit
// vmcnt(0) drain lands after the loads had the full compute phase in flight
// (vs the old structure's drain immediately after issue = zero overlap).
// Hazard: stage at iter t overwrites data last read at t-1, whose reads
// complete before t-1's barrier -> safe. ds_read waits lgkmcnt only, so the
// fresh glds (vmcnt) don't block it.
template <int KDIM, int KA, int MODE, int MT, int NBLK, int BMAJ = 0, int NTW = 128>
__global__ __launch_bounds__(256) void k_gemm_bt(const unsigned short* __restrict__ A,
                                                 const unsigned short* __restrict__ B,
                                                 float* __restrict__ O0f,
                                                 unsigned short* __restrict__ O0h,
                                                 unsigned short* __restrict__ O1h) {
  __shared__ unsigned short As[2][128 * 32];
  __shared__ unsigned short Bs[2][NTW * 32];
  constexpr int Q = NBLK / 8, R = NBLK % 8;
  constexpr int NFR = NTW / 32;  // n-frags per wave (128->4, 64->2)
  int xcd = blockIdx.x & 7;
  int slot = blockIdx.x >> 3;
  int start = xcd * Q + (xcd < R ? xcd : R);
  int j = start + slot;
  int m0 = (j % MT) * 128;
  int n0 = (j / MT) * NTW;
  int tid = threadIdx.x;
  int lane = tid & 63;
  int wm = (tid >> 6) & 1;
  int wn = tid >> 7;
  int srow = tid >> 2;
  // source k-slot permuted by the LDS swizzle involution (row = tid>>2)
  int skof = (((tid & 3) ^ ((tid >> 3) & 3)) * 8);
  int brow0 = n0 + srow;       if (brow0 >= NBL) brow0 = NBL - 1;
  int brow1 = n0 + srow + 64;  if (brow1 >= NBL) brow1 = NBL - 1;  // NTW==128 only
  size_t rb0a = 0, rb0b = 0, rb0c = 0, rb1a = 0, rb1b = 0, rb1c = 0;
  if (BMAJ) {
    int bb0 = brow0 >= L_SEQ ? 1 : 0, l0 = brow0 - bb0 * L_SEQ;
    int t1_0 = L_SEQ - 1 - l0;
    int t2_0 = 5 * (l0 % 800) + l0 / 800;
    rb0a = ((size_t)(0 + bb0) * L_SEQ + l0) * DI;
    rb0b = ((size_t)(2 + bb0) * L_SEQ + t1_0) * DI;
    rb0c = ((size_t)(4 + bb0) * L_SEQ + t2_0) * DI;
    if (NTW == 128) {
      int bb1 = brow1 >= L_SEQ ? 1 : 0, l1 = brow1 - bb1 * L_SEQ;
      int t1_1 = L_SEQ - 1 - l1;
      int t2_1 = 5 * (l1 % 800) + l1 / 800;
      rb1a = ((size_t)(0 + bb1) * L_SEQ + l1) * DI;
      rb1b = ((size_t)(2 + bb1) * L_SEQ + t1_1) * DI;
      rb1c = ((size_t)(4 + bb1) * L_SEQ + t2_1) * DI;
    }
  }
  auto stage = [&](int buf, int k0) {
    int ka = (k0 % KA);
    glds16(&A[(size_t)(m0 + srow) * KA + ka + skof],      &As[buf][tid * 8]);
    glds16(&A[(size_t)(m0 + srow + 64) * KA + ka + skof], &As[buf][tid * 8 + 2048]);
    if (BMAJ) {
      int brnk = k0 / DI;
      int dd0 = k0 - brnk * DI;
      size_t b0 = brnk == 0 ? rb0a : (brnk == 1 ? rb0b : rb0c);
      glds16(&B[b0 + dd0 + skof], &Bs[buf][tid * 8]);
      if (NTW == 128) {
        size_t b1 = brnk == 0 ? rb1a : (brnk == 1 ? rb1b : rb1c);
        glds16(&B[b1 + dd0 + skof], &Bs[buf][tid * 8 + 2048]);
      }
    } else {
      glds16(&B[(size_t)brow0 * KDIM + k0 + skof], &Bs[buf][tid * 8]);
      if (NTW == 128)
        glds16(&B[(size_t)brow1 * KDIM + k0 + skof], &Bs[buf][tid * 8 + 2048]);
    }
  };
  floatx4 zero = {0.f, 0.f, 0.f, 0.f};
  floatx4 acc[4][NFR];
#pragma unroll
  for (int i = 0; i < 4; ++i)
#pragma unroll
    for (int j2 = 0; j2 < NFR; ++j2) acc[i][j2] = zero;
  int ar = wm * 64 + (lane & 15);
  int br = wn * (NTW / 2) + (lane & 15);
  // fragment read: logical slot lane>>4 at physical slot ^((row>>1)&3);
  // (row>>1)&3 == (lane>>1)&3 for all row bases used here (multiples of 16).
  int kq = (((lane >> 4) ^ ((lane >> 1) & 3)) * 8);
  stage(0, 0);
  __syncthreads();
  int cur = 0;
  for (int k0 = 0; k0 < KDIM; k0 += 32) {
    if (k0 + 32 < KDIM) stage(cur ^ 1, k0 + 32);
    short8 a[4], b[NFR];
#pragma unroll
    for (int i = 0; i < 4; ++i) a[i] = *(const short8*)&As[cur][(ar + i * 16) * 32 + kq];
#pragma unroll
    for (int i = 0; i < NFR; ++i) b[i] = *(const short8*)&Bs[cur][(br + i * 16) * 32 + kq];
#pragma unroll
    for (int mt = 0; mt < 4; ++mt)
#pragma unroll
      for (int nt = 0; nt < NFR; ++nt)
        acc[mt][nt] = __builtin_amdgcn_mfma_f32_16x16x32_bf16(a[mt], b[nt], acc[mt][nt], 0, 0, 0);
    __syncthreads();
    cur ^= 1;
  }
  int mq = m0 + wm * 64 + ((lane >> 4) << 2);
  int nq = n0 + wn * (NTW / 2) + (lane & 15);
#pragma unroll
  for (int nt = 0; nt < NFR; ++nt) {
    int n = nq + nt * 16;
    if (n >= NBL) continue;
#pragma unroll
    for (int mt = 0; mt < 4; ++mt) {
      int m = mq + mt * 16;
      floatx4 v = acc[mt][nt];
      if (MODE == 0) {
        *(floatx4*)&O0f[(size_t)n * DM + m] = v;
      } else {
        if (m < DI) {
          ushort4v r;
          r[0] = f2bf(v[0]); r[1] = f2bf(v[1]); r[2] = f2bf(v[2]); r[3] = f2bf(v[3]);
          *(ushort4v*)&O0h[(size_t)n * DI + m] = r;
        } else {
          ushort4v r;
          r[0] = f2bf(silu_f(v[0])); r[1] = f2bf(silu_f(v[1]));
          r[2] = f2bf(silu_f(v[2])); r[3] = f2bf(silu_f(v[3]));
          *(ushort4v*)&O1h[(size_t)n * DI + m - DI] = r;
        }
      }
    }
  }
}

// ---------------- conv+silu materialization: xTB[b][l][d] -> xaB[z][t][d] bf16 ----------------
__global__ __launch_bounds__(256) void k_conv_all(const unsigned short* __restrict__ xTB,
                                                  const float* __restrict__ cw_all,
                                                  unsigned short* __restrict__ xaB) {
  int z = blockIdx.z;
  int brn = z >> 1, b = z & 1;
  int d = blockIdx.x * 256 + threadIdx.x;
  int t0 = blockIdx.y * 8;
  const unsigned short* xrow = xTB + (size_t)b * L_SEQ * DI;
  float4 w = *(const float4*)&cw_all[((size_t)brn * DI + d) * 4];
  float xm3 = (t0 >= 3) ? bf2f(xrow[(size_t)map_t(brn, t0 - 3) * DI + d]) : 0.f;
  float xm2 = (t0 >= 2) ? bf2f(xrow[(size_t)map_t(brn, t0 - 2) * DI + d]) : 0.f;
  float xm1 = (t0 >= 1) ? bf2f(xrow[(size_t)map_t(brn, t0 - 1) * DI + d]) : 0.f;
#pragma unroll
  for (int i = 0; i < 8; ++i) {
    int t = t0 + i;
    float xc = bf2f(xrow[(size_t)map_t(brn, t) * DI + d]);
    float xa = silu_f(fmaf(w.w, xc, fmaf(w.z, xm1, fmaf(w.y, xm2, w.x * xm3))));
    xaB[((size_t)z * L_SEQ + t) * DI + d] = f2bf(xa);
    xm3 = xm2; xm2 = xm1; xm1 = xc;
  }
}

// ---------------- xproj MFMA: C[j][t] = sum_d xpw[j][d]*xa[z][t][d] ----------------
// Same T2 k-slot XOR swizzle as k_gemm_bt.
__global__ __launch_bounds__(256) void k_xprojm(const unsigned short* __restrict__ xpwB,
                                                const unsigned short* __restrict__ xaB,
                                                unsigned short* __restrict__ dtrB,
                                                float* __restrict__ BC) {
  __shared__ unsigned short As[128 * 32];
  __shared__ unsigned short Bs[128 * 32];
  int z = blockIdx.z;
  int brn = z >> 1;
  int n0 = blockIdx.x * 128;
  int tid = threadIdx.x;
  int lane = tid & 63;
  int wm = (tid >> 6) & 1;
  int wn = tid >> 7;
  int srow = tid >> 2;
  int skof = (((tid & 3) ^ ((tid >> 3) & 3)) * 8);
  int arow0 = srow;       if (arow0 > 79) arow0 = 79;
  int arow1 = srow + 64;  if (arow1 > 79) arow1 = 79;
  int brow0 = n0 + srow;       if (brow0 >= L_SEQ) brow0 = L_SEQ - 1;
  int brow1 = n0 + srow + 64;  if (brow1 >= L_SEQ) brow1 = L_SEQ - 1;
  const unsigned short* A = xpwB + (size_t)brn * 80 * DI;
  const unsigned short* Bm = xaB + (size_t)z * L_SEQ * DI;
  floatx4 zero = {0.f, 0.f, 0.f, 0.f};
  floatx4 acc[4][4];
#pragma unroll
  for (int i = 0; i < 4; ++i)
#pragma unroll
    for (int j = 0; j < 4; ++j) acc[i][j] = zero;
  int ar = wm * 64 + (lane & 15);
  int br = wn * 64 + (lane & 15);
  int kq = (((lane >> 4) ^ ((lane >> 1) & 3)) * 8);
  for (int k0 = 0; k0 < DI; k0 += 32) {
    glds16(&A[(size_t)arow0 * DI + k0 + skof], &As[tid * 8]);
    glds16(&A[(size_t)arow1 * DI + k0 + skof], &As[tid * 8 + 2048]);
    glds16(&Bm[(size_t)brow0 * DI + k0 + skof], &Bs[tid * 8]);
    glds16(&Bm[(size_t)brow1 * DI + k0 + skof], &Bs[tid * 8 + 2048]);
    __syncthreads();
    short8 a[4], b[4];
#pragma unroll
    for (int i = 0; i < 4; ++i) a[i] = *(const short8*)&As[(ar + i * 16) * 32 + kq];
#pragma unroll
    for (int i = 0; i < 4; ++i) b[i] = *(const short8*)&Bs[(br + i * 16) * 32 + kq];
#pragma unroll
    for (int mt = 0; mt < 4; ++mt)
#pragma unroll
      for (int nt = 0; nt < 4; ++nt)
        acc[mt][nt] = __builtin_amdgcn_mfma_f32_16x16x32_bf16(a[mt], b[nt], acc[mt][nt], 0, 0, 0);
    __syncthreads();
  }
  int mq = wm * 64 + ((lane >> 4) << 2);
  int nq = n0 + wn * 64 + (lane & 15);
#pragma unroll
  for (int nt = 0; nt < 4; ++nt) {
    int t = nq + nt * 16;
    if (t >= L_SEQ) continue;
#pragma unroll
    for (int mt = 0; mt < 4; ++mt) {
      int j = mq + mt * 16;
      if (j >= 80) continue;
      floatx4 v = acc[mt][nt];
      if (j < 48) {
        ushort4v r;
        r[0] = f2bf(v[0]); r[1] = f2bf(v[1]); r[2] = f2bf(v[2]); r[3] = f2bf(v[3]);
        *(ushort4v*)&dtrB[((size_t)z * L_SEQ + t) * DTRK + j] = r;
      } else {
#pragma unroll
        for (int r = 0; r < 4; ++r)
          BC[((size_t)z * 32 + (j + r - 48)) * L_SEQ + t] = v[r];
      }
    }
  }
}

// ---------------- delta GEMM (MFMA, K=48 padded to 64) + softplus -> bf16 [z][t][d]
// LDS layout XOR-swizzled: row of 64 shorts = 8 slots of 8 shorts; data for
// slot s of row r lives at slot s^(r&7). Fixes 16-way read / 32-way write
// bank conflicts of the linear 128-B-stride layout.
__global__ __launch_bounds__(256) void k_dtg(const unsigned short* __restrict__ dpwB,
                                             const unsigned short* __restrict__ dtrB,
                                             const float* __restrict__ dbias,
                                             unsigned short* __restrict__ dT) {
  __shared__ unsigned short As[128 * 64];
  __shared__ unsigned short Bs[128 * 64];
  int z = blockIdx.z;
  int brn = z >> 1;
  int m0 = blockIdx.y * 128;
  int n0 = blockIdx.x * 128;
  int tid = threadIdx.x;
  int lane = tid & 63;
  int wm = (tid >> 6) & 1;
  int wn = tid >> 7;
  {
    int zr = tid >> 1, zs = 6 + (tid & 1);
    ushort8 zz = {0, 0, 0, 0, 0, 0, 0, 0};
    *(ushort8*)&As[zr * 64 + ((zs ^ (zr & 7)) << 3)] = zz;
    *(ushort8*)&Bs[zr * 64 + ((zs ^ (zr & 7)) << 3)] = zz;
  }
  {
    int row = tid >> 1;
    int p0 = (tid & 1) * 3;
    const unsigned short* Ag = dpwB + (size_t)brn * DI * DTRK + (size_t)(m0 + row) * DTRK;
    int bro = n0 + row; if (bro > L_SEQ - 1) bro = L_SEQ - 1;
    const unsigned short* Bg = dtrB + ((size_t)z * L_SEQ + bro) * DTRK;
#pragma unroll
    for (int i = 0; i < 3; ++i) {
      int slot = p0 + i;
      int off = (slot ^ (row & 7)) << 3;
      *(ushort8*)&As[row * 64 + off] = *(const ushort8*)&Ag[slot << 3];
      *(ushort8*)&Bs[row * 64 + off] = *(const ushort8*)&Bg[slot << 3];
    }
  }
  __syncthreads();
  int ar = wm * 64 + (lane & 15);
  int brr = wn * 64 + (lane & 15);
  int kslot = lane >> 4;  // 0..3
  floatx4 zero = {0.f, 0.f, 0.f, 0.f};
  floatx4 acc[4][4];
#pragma unroll
  for (int i = 0; i < 4; ++i)
#pragma unroll
    for (int j = 0; j < 4; ++j) acc[i][j] = zero;
#pragma unroll
  for (int kk = 0; kk < 2; ++kk) {
    short8 a[4], b[4];
    int slot = kk * 4 + kslot;
#pragma unroll
    for (int i = 0; i < 4; ++i) {
      int r = ar + i * 16;
      a[i] = *(const short8*)&As[r * 64 + ((slot ^ (r & 7)) << 3)];
    }
#pragma unroll
    for (int i = 0; i < 4; ++i) {
      int r = brr + i * 16;
      b[i] = *(const short8*)&Bs[r * 64 + ((slot ^ (r & 7)) << 3)];
    }
#pragma unroll
    for (int mt = 0; mt < 4; ++mt)
#pragma unroll
      for (int nt = 0; nt < 4; ++nt)
        acc[mt][nt] = __builtin_amdgcn_mfma_f32_16x16x32_bf16(a[mt], b[nt], acc[mt][nt], 0, 0, 0);
  }
  int mq = m0 + wm * 64 + ((lane >> 4) << 2);
  int nq = n0 + wn * 64 + (lane & 15);
  float4 bi[4];
#pragma unroll
  for (int mt = 0; mt < 4; ++mt)
    bi[mt] = *(const float4*)&dbias[(size_t)brn * DI + mq + mt * 16];
#pragma unroll
  for (int nt = 0; nt < 4; ++nt) {
    int n = nq + nt * 16;
    if (n >= L_SEQ) continue;
#pragma unroll
    for (int mt = 0; mt < 4; ++mt) {
      int m = mq + mt * 16;
      floatx4 v = acc[mt][nt];
      ushort4v r;
      r[0] = f2bf(softplus_f(v[0] + bi[mt].x));
      r[1] = f2bf(softplus_f(v[1] + bi[mt].y));
      r[2] = f2bf(softplus_f(v[2] + bi[mt].z));
      r[3] = f2bf(softplus_f(v[3] + bi[mt].w));
      *(ushort4v*)&dT[((size_t)z * L_SEQ + n) * DI + m] = r;
    }
  }
}

__device__ __forceinline__ void load_a2(const float* __restrict__ A_log, int brn, int d,
                                        float* a2, bool& fastp) {
  fastp = true;
#pragma unroll
  for (int g = 0; g < 4; ++g) {
    float4 v = *(const float4*)&A_log[((size_t)brn * DI + d) * DS + g * 4];
    float av0 = __expf(v.x), av1 = __expf(v.y), av2 = __expf(v.z), av3 = __expf(v.w);
    a2[g * 4 + 0] = -av0 * 1.44269504f; a2[g * 4 + 1] = -av1 * 1.44269504f;
    a2[g * 4 + 2] = -av2 * 1.44269504f; a2[g * 4 + 3] = -av3 * 1.44269504f;
    fastp = fastp && fabsf(av0 - (float)(g * 4 + 1)) < 1e-3f
                  && fabsf(av1 - (float)(g * 4 + 2)) < 1e-3f
                  && fabsf(av2 - (float)(g * 4 + 3)) < 1e-3f
                  && fabsf(av3 - (float)(g * 4 + 4)) < 1e-3f;
  }
}

// ---------------- scan phase 1: per-chunk local state + delta-sum ----------------
// raw-bf16 pipeline slots: loads issue with NO attached conversion; bf2f happens
// only at the consuming body, 3 bodies later -> counted vmcnt, ~12 loads in flight.
#define S1_BODY(T, XV, DLV)                                                       \
  do {                                                                            \
    S += (DLV);                                                                   \
    float dtx_ = (DLV) * (XV);                                                    \
    float2v dc2[8];                                                               \
    if (fastp) {                                                                  \
      pow_ladder2(exp2f(-(DLV) * 1.44269504f), dc2);                              \
    } else {                                                                      \
      _Pragma("unroll")                                                           \
      for (int i = 0; i < 8; ++i)                                                 \
        dc2[i] = (float2v){exp2f((DLV) * a2[2 * i]), exp2f((DLV) * a2[2 * i + 1])}; \
    }                                                                             \
    const float2v* B2 = (const float2v*)&BtS[(T)][0];                             \
    float2v dtx2 = {dtx_, dtx_};                                                  \
    _Pragma("unroll")                                                             \
    for (int i = 0; i < 8; ++i)                                                   \
      h2[i] = __builtin_elementwise_fma(h2[i], dc2[i], dtx2 * B2[i]);             \
  } while (0)

__global__ __launch_bounds__(256) void k_scan1c(const unsigned short* __restrict__ xaB,
                                                const unsigned short* __restrict__ dT,
                                                const float* __restrict__ BC,
                                                const float* __restrict__ A_log,
                                                float* __restrict__ hO,
                                                float* __restrict__ Sc) {
  __shared__ float BtS[LC][16];
  int z = blockIdx.z;
  int brn = z >> 1;
  int ch = blockIdx.y;
  int t0 = ch * LC;
  int d = blockIdx.x * 256 + threadIdx.x;
  int tid = threadIdx.x;
  for (int i = tid; i < 320; i += 256) {
    int row = i / 20;
    int c4 = (i % 20) * 4;
    float4 v = *(const float4*)&BC[((size_t)z * 32 + row) * L_SEQ + t0 + c4];
    BtS[c4 + 0][row] = v.x; BtS[c4 + 1][row] = v.y;
    BtS[c4 + 2][row] = v.z; BtS[c4 + 3][row] = v.w;
  }
  float a2[16]; bool fastp;
  load_a2(A_log, brn, d, a2, fastp);
  const unsigned short* xbp = xaB + ((size_t)z * L_SEQ + t0) * DI + d;
  const unsigned short* dbp = dT + ((size_t)z * L_SEQ + t0) * DI + d;
  float2v h2[8];
#pragma unroll
  for (int i = 0; i < 8; ++i) h2[i] = (float2v){0.f, 0.f};
  float S = 0.f;
  // preload 4 raw slots (tt = 0..3)
  unsigned short rx_a = xbp[0],      rd_a = dbp[0];
  unsigned short rx_b = xbp[DI],     rd_b = dbp[DI];
  unsigned short rx_c = xbp[2 * DI], rd_c = dbp[2 * DI];
  unsigned short rx_d = xbp[3 * DI], rd_d = dbp[3 * DI];
  __syncthreads();
  for (int t4 = 0; t4 < LC; t4 += 4) {
    { float xv = bf2f(rx_a), dv = bf2f(rd_a); S1_BODY(t4 + 0, xv, dv); }
    { int tc = (t4 + 4 < LC) ? t4 + 4 : LC - 1; rx_a = xbp[tc * DI]; rd_a = dbp[tc * DI]; }
    { float xv = bf2f(rx_b), dv = bf2f(rd_b); S1_BODY(t4 + 1, xv, dv); }
    { int tc = (t4 + 5 < LC) ? t4 + 5 : LC - 1; rx_b = xbp[tc * DI]; rd_b = dbp[tc * DI]; }
    { float xv = bf2f(rx_c), dv = bf2f(rd_c); S1_BODY(t4 + 2, xv, dv); }
    { int tc = (t4 + 6 < LC) ? t4 + 6 : LC - 1; rx_c = xbp[tc * DI]; rd_c = dbp[tc * DI]; }
    { float xv = bf2f(rx_d), dv = bf2f(rd_d); S1_BODY(t4 + 3, xv, dv); }
    { int tc = (t4 + 7 < LC) ? t4 + 7 : LC - 1; rx_d = xbp[tc * DI]; rd_d = dbp[tc * DI]; }
  }
  size_t base = (((size_t)z * NCH + ch) * DI + d) * 16;
#pragma unroll
  for (int i = 0; i < 8; ++i) *(float2v*)&hO[base + i * 2] = h2[i];
  Sc[((size_t)z * NCH + ch) * DI + d] = S;
}

// ---------------- scan phase 2: sequential combine over chunks (depth-4 prefetch) ----------------
__global__ __launch_bounds__(256) void k_scan2c(float* __restrict__ hO,
                                                const float* __restrict__ Sc,
                                                const float* __restrict__ A_log) {
  int idx = blockIdx.x * 256 + threadIdx.x;
  int z = idx / (DI * 16);
  int rem = idx % (DI * 16);
  int brn = z >> 1;
  float a2 = -__expf(A_log[(size_t)brn * DI * DS + rem]) * 1.44269504f;
  const int HS = DI * 16;
  size_t p = (size_t)z * NCH * HS + rem;
  size_t q = (size_t)z * NCH * DI + (rem >> 4);
  float th_a = hO[p];            float s_a = Sc[q];
  float th_b = hO[p + HS];       float s_b = Sc[q + DI];
  float th_c = hO[p + 2 * HS];   float s_c = Sc[q + 2 * DI];
  float th_d = hO[p + 3 * HS];   float s_d = Sc[q + 3 * DI];
  float H = 0.f;
  for (int c4 = 0; c4 < 48; c4 += 4) {
    hO[p] = H; H = fmaf(exp2f(s_a * a2), H, th_a);
    th_a = hO[p + 4 * HS]; s_a = Sc[q + 4 * DI];        // c4+4 <= 48 always
    p += HS; q += DI;
    hO[p] = H; H = fmaf(exp2f(s_b * a2), H, th_b);
    th_b = hO[p + 4 * HS]; s_b = Sc[q + 4 * DI];        // c4+5 <= 49 always
    p += HS; q += DI;
    hO[p] = H; H = fmaf(exp2f(s_c * a2), H, th_c);
    if (c4 + 6 < NCH) { th_c = hO[p + 4 * HS]; s_c = Sc[q + 4 * DI]; }
    p += HS; q += DI;
    hO[p] = H; H = fmaf(exp2f(s_d * a2), H, th_d);
    if (c4 + 7 < NCH) { th_d = hO[p + 4 * HS]; s_d = Sc[q + 4 * DI]; }
    p += HS; q += DI;
  }
  // tail: c = 48, 49
  hO[p] = H; H = fmaf(exp2f(s_a * a2), H, th_a); p += HS;
  hO[p] = H;
}

// ---------------- scan phase 3: reads xaB + dT, writes y*sz IN PLACE into dT ----
// Each dT element (z,t,d) is consumed by exactly one thread at exactly one body,
// then overwritten by that same thread (read runs 4 steps ahead of the write)
// -> no inter-thread hazard, no ybuf. The branch-time->output-position
// permutation is resolved by the out-proj GEMM's B-row gather (BMAJ=1).
#define S3D(T, XV, DLV, SZV)                                                      \
  do {                                                                            \
    float dtx_ = (DLV) * (XV);                                                    \
    float2v dc2[8];                                                               \
    if (fastp) {                                                                  \
      pow_ladder2(exp2f(-(DLV) * 1.44269504f), dc2);                              \
    } else {                                                                      \
      _Pragma("unroll")                                                           \
      for (int i = 0; i < 8; ++i)                                                 \
        dc2[i] = (float2v){exp2f((DLV) * a2[2 * i]), exp2f((DLV) * a2[2 * i + 1])}; \
    }                                                                             \
    const float2v* B2 = (const float2v*)&BCt[(T)][0];                             \
    const float2v* C2 = (const float2v*)&BCt[(T)][16];                            \
    float2v dtx2 = {dtx_, dtx_};                                                  \
    float2v y2a = {0.f, 0.f}, y2b = {0.f, 0.f};                                   \
    _Pragma("unroll")                                                             \
    for (int i = 0; i < 4; ++i) {                                                 \
      h2[i] = __builtin_elementwise_fma(h2[i], dc2[i], dtx2 * B2[i]);             \
      y2a = __builtin_elementwise_fma(h2[i], C2[i], y2a);                         \
    }                                                                             \
    _Pragma("unroll")                                                             \
    for (int i = 4; i < 8; ++i) {                                                 \
      h2[i] = __builtin_elementwise_fma(h2[i], dc2[i], dtx2 * B2[i]);             \
      y2b = __builtin_elementwise_fma(h2[i], C2[i], y2b);                         \
    }                                                                             \
    float y_ = (y2a[0] + y2a[1]) + (y2b[0] + y2b[1]) + Dv * (XV);                 \
    dp[(size_t)(T) * DI] = f2bf(y_ * (SZV));                                      \
  } while (0)

__global__ __launch_bounds__(256) void k_scan3d(const unsigned short* __restrict__ xaB,
                                                unsigned short* __restrict__ dT,
                                                const float* __restrict__ BC,
                                                const float* __restrict__ A_log,
                                                const float* __restrict__ Dp,
                                                const float* __restrict__ hO,
                                                const unsigned short* __restrict__ szTB) {
  __shared__ float BCt[LC][32];
  int z = blockIdx.z;
  int brn = z >> 1, b = z & 1;
  int ch = blockIdx.y;
  int t0 = ch * LC;
  int d = blockIdx.x * 256 + threadIdx.x;
  int tid = threadIdx.x;
  for (int i = tid; i < 640; i += 256) {
    int row = i / 20;
    int c4 = (i % 20) * 4;
    float4 v = *(const float4*)&BC[((size_t)z * 32 + row) * L_SEQ + t0 + c4];
    BCt[c4 + 0][row] = v.x; BCt[c4 + 1][row] = v.y;
    BCt[c4 + 2][row] = v.z; BCt[c4 + 3][row] = v.w;
  }
  float a2[16]; bool fastp;
  load_a2(A_log, brn, d, a2, fastp);
  float Dv = Dp[(size_t)brn * DI + d];
  const unsigned short* xp = xaB + ((size_t)z * L_SEQ + t0) * DI + d;
  unsigned short* dp = dT + ((size_t)z * L_SEQ + t0) * DI + d;
  const unsigned short* szb = szTB + (size_t)b * L_SEQ * DI + d;
  float2v h2[8];
  size_t hbase = (((size_t)z * NCH + ch) * DI + d) * 16;
#pragma unroll
  for (int i = 0; i < 8; ++i) h2[i] = *(const float2v*)&hO[hbase + i * 2];
  // closed-form in-chunk row map (sz gather only; xa/del/store are sequential).
  bool isb2 = (brn == 2);
  int mbase = (brn == 1) ? (L_SEQ - 1 - t0) : t0;
  int msign = (brn == 1) ? -1 : 1;
  int chb = ch * 16;
  auto mrow = [&](int tt) -> int {
    if (isb2) return (tt % 5) * 800 + chb + tt / 5;
    return mbase + msign * tt;
  };
  // preload 4 raw slots (tt = 0..3)
  unsigned short rx_a = xp[0],      rl_a = dp[0],      rs_a = szb[(size_t)mrow(0) * DI];
  unsigned short rx_b = xp[DI],     rl_b = dp[DI],     rs_b = szb[(size_t)mrow(1) * DI];
  unsigned short rx_c = xp[2 * DI], rl_c = dp[2 * DI], rs_c = szb[(size_t)mrow(2) * DI];
  unsigned short rx_d = xp[3 * DI], rl_d = dp[3 * DI], rs_d = szb[(size_t)mrow(3) * DI];
  __syncthreads();
  for (int t4 = 0; t4 < LC; t4 += 4) {
    { float xv = bf2f(rx_a), dv = bf2f(rl_a), sv = bf2f(rs_a); S3D(t4 + 0, xv, dv, sv); }
    { int tc = (t4 + 4 < LC) ? t4 + 4 : LC - 1;
      rx_a = xp[(size_t)tc * DI]; rl_a = dp[(size_t)tc * DI]; rs_a = szb[(size_t)mrow(tc) * DI]; }
    { float xv = bf2f(rx_b), dv = bf2f(rl_b), sv = bf2f(rs_b); S3D(t4 + 1, xv, dv, sv); }
    { int tc = (t4 + 5 < LC) ? t4 + 5 : LC - 1;
      rx_b = xp[(size_t)tc * DI]; rl_b = dp[(size_t)tc * DI]; rs_b = szb[(size_t)mrow(tc) * DI]; }
    { float xv = bf2f(rx_c), dv = bf2f(rl_c), sv = bf2f(rs_c); S3D(t4 + 2, xv, dv, sv); }
    { int tc = (t4 + 6 < LC) ? t4 + 6 : LC - 1;
      rx_c = xp[(size_t)tc * DI]; rl_c = dp[(size_t)tc * DI]; rs_c = szb[(size_t)mrow(tc) * DI]; }
    { float xv = bf2f(rx_d), dv = bf2f(rl_d), sv = bf2f(rs_d); S3D(t4 + 3, xv, dv, sv); }
    { int tc = (t4 + 7 < LC) ? t4 + 7 : LC - 1;
      rx_d = xp[(size_t)tc * DI]; rl_d = dp[(size_t)tc * DI]; rs_d = szb[(size_t)mrow(tc) * DI]; }
  }
}

extern "C" void kernel_launch(void* const* d_in, const int* in_sizes, int n_in,
                              void* d_out, int out_size, void* d_ws, size_t ws_size,
                              hipStream_t stream) {
  const float* hs        = (const float*)d_in[0];
  const float* in_proj_w = (const float*)d_in[1];
  const float* conv_w    = (const float*)d_in[2];
  const float* x_proj_w  = (const float*)d_in[3];
  const float* dt_proj_w = (const float*)d_in[4];
  const float* dt_bias   = (const float*)d_in[5];
  const float* A_log     = (const float*)d_in[6];
  const float* D_param   = (const float*)d_in[7];
  const float* out_proj_w= (const float*)d_in[8];
  float* out = (float*)d_out;
  float* ws = (float*)d_ws;

  unsigned short* xTB  = (unsigned short*)(ws);             // 12,288,000 sh
  unsigned short* szTB = (unsigned short*)(ws + 6144000);   // 12,288,000 sh
  unsigned short* dtrB = (unsigned short*)(ws + 12288000);  // 1,152,000 sh
  float* BC            = ws + 12864000;                     // 768,000 f
  unsigned short* dT   = (unsigned short*)(ws + 13632000);  // 36,864,000 sh (delta, then y in place)
  float* hO            = ws + 32064000;                     // 7,372,800 f
  float* Sc            = ws + 39436800;                     // 460,800 f
  unsigned short* dpwB = (unsigned short*)(ws + 39897600);  // 221,184 sh
  unsigned short* OWb  = (unsigned short*)(ws + 40008192);  // 1,179,648 sh
  // region R (disjoint lifetimes): {hsB, Wb} -> {xaB}; xaB stays live through scan3d
  unsigned short* hsB  = (unsigned short*)(ws + 40598016);  // 6,144,000 sh
  unsigned short* Wb   = hsB + 6144000;                     // 2,359,296 sh
  unsigned short* xaB  = (unsigned short*)(ws + 40598016);  // 36,864,000 sh
  unsigned short* xpwB = (unsigned short*)(ws + 59030016);  // 368,640 sh

  k_cast5<<<5016, 256, 0, stream>>>(hs, hsB, in_proj_w, Wb, out_proj_w, OWb,
                                    dt_proj_w, dpwB, x_proj_w, xpwB);

  // in-proj: 24 m-tiles x 63 n-tiles = 1512 blocks, XCD-chunked n-major swizzle
  k_gemm_bt<DM, DM, 1, 24, 1512><<<1512, 256, 0, stream>>>(Wb, hsB, nullptr, xTB, szTB);

  k_conv_all<<<dim3(6, 500, 6), 256, 0, stream>>>(xTB, conv_w, xaB);
  k_xprojm<<<dim3(32, 1, 6), 256, 0, stream>>>(xpwB, xaB, dtrB, BC);
  k_dtg<<<dim3(32, 12, 6), 256, 0, stream>>>(dpwB, dtrB, dt_bias, dT);

  k_scan1c<<<dim3(6, NCH, 6), 256, 0, stream>>>(xaB, dT, BC, A_log, hO, Sc);
  k_scan2c<<<576, 256, 0, stream>>>(hO, Sc, A_log);
  // scan3: reads xaB (kept live), writes y*sz in place into dT
  k_scan3d<<<dim3(6, NCH, 6), 256, 0, stream>>>(xaB, dT, BC, A_log, D_param, hO, szTB);

  // out-proj: B = dT branch-major gather (BMAJ=1), 64-wide n-tiles:
  // 6 m-tiles x 125 n-tiles = 750 blocks (~3/CU) to hide per-iter latency
  k_gemm_bt<3 * DI, DI, 0, 6, 750, 1, 64><<<750, 256, 0, stream>>>(OWb, dT, out, nullptr, nullptr);
}

// Round 12
// 580.216 us; speedup vs baseline: 1.1756x; 1.1756x over previous
//
#include <hip/hip_runtime.h>
#include <math.h>

#define L_SEQ 4000
#define DM 768
#define DI 1536
#define DS 16
#define DTRK 48
#define NCH 50
#define LC 80
#define NBL 8000

typedef __attribute__((ext_vector_type(8))) short short8;
typedef __attribute__((ext_vector_type(8))) unsigned short ushort8;
typedef __attribute__((ext_vector_type(4))) unsigned short ushort4v;
typedef __attribute__((ext_vector_type(4))) float floatx4;
typedef __attribute__((ext_vector_type(2))) float float2v;

__device__ __forceinline__ float silu_f(float x) { return x / (1.f + __expf(-x)); }
// fast softplus: log1pf -> __logf(1+e); e>0 so no cancellation; when 1+e rounds
// to 1 the true value <= 6e-8, invisible in bf16 output.
__device__ __forceinline__ float softplus_f(float x) {
  return fmaxf(x, 0.f) + __logf(1.f + __expf(-fabsf(x)));
}
__device__ __forceinline__ int map_t(int branch, int t) {
  if (branch == 0) return t;
  if (branch == 1) return L_SEQ - 1 - t;
  return (t % 5) * 800 + t / 5;
}
__device__ __forceinline__ unsigned short f2bf(float f) {
  unsigned int u = __float_as_uint(f);
  u = (u + 0x7fffu + ((u >> 16) & 1u)) >> 16;
  return (unsigned short)u;
}
__device__ __forceinline__ float bf2f(unsigned short u) {
  return __uint_as_float(((unsigned int)u) << 16);
}
__device__ __forceinline__ void glds16(const void* g, void* l) {
  __builtin_amdgcn_global_load_lds((const __attribute__((address_space(1))) void*)g,
                                   (__attribute__((address_space(3))) void*)l, 16, 0, 0);
}
// packed power ladder, TREE form (dep depth 4 vs 8 of the serial ladder):
// dc2[i] = {E^(2i+1), E^(2i+2)} for i=0..7, built from E2/E4/E8 squarings.
__device__ __forceinline__ void pow_ladder2(float E1, float2v* dc2) {
  float E2 = E1 * E1;
  float E4 = E2 * E2;
  float E8 = E4 * E4;
  float2v v4 = {E4, E4}, v8 = {E8, E8};
  dc2[0] = (float2v){E1, E2};
  dc2[1] = dc2[0] * (float2v){E2, E2};  // E3,E4
  dc2[2] = dc2[0] * v4;                 // E5,E6
  dc2[3] = dc2[1] * v4;                 // E7,E8
  dc2[4] = dc2[0] * v8;                 // E9,E10
  dc2[5] = dc2[1] * v8;                 // E11,E12
  dc2[6] = dc2[2] * v8;                 // E13,E14
  dc2[7] = dc2[3] * v8;                 // E15,E16
}

// ---------------- merged cast fp32 -> bf16 for all 5 weight/input arrays ----------------
__device__ __forceinline__ void cast_seg(const float* __restrict__ src,
                                         unsigned short* __restrict__ dst,
                                         int blk, int n) {
  int i = (blk * 256 + (int)threadIdx.x) * 8;
  if (i >= n) return;
  float4 v0 = *(const float4*)&src[i];
  float4 v1 = *(const float4*)&src[i + 4];
  ushort8 r;
  r[0] = f2bf(v0.x); r[1] = f2bf(v0.y); r[2] = f2bf(v0.z); r[3] = f2bf(v0.w);
  r[4] = f2bf(v1.x); r[5] = f2bf(v1.y); r[6] = f2bf(v1.z); r[7] = f2bf(v1.w);
  *(ushort8*)&dst[i] = r;
}
__global__ __launch_bounds__(256) void k_cast5(const float* s0, unsigned short* d0,
                                               const float* s1, unsigned short* d1,
                                               const float* s2, unsigned short* d2,
                                               const float* s3, unsigned short* d3,
                                               const float* s4, unsigned short* d4) {
  int blk = blockIdx.x;
  if (blk < 3000)      cast_seg(s0, d0, blk,        6144000);
  else if (blk < 4152) cast_seg(s1, d1, blk - 3000, 2359296);
  else if (blk < 4728) cast_seg(s2, d2, blk - 4152, 1179648);
  else if (blk < 4836) cast_seg(s3, d3, blk - 4728, 221184);
  else                 cast_seg(s4, d4, blk - 4836, 368640);
}

// ---------------- MFMA GEMM (bt): C[m][n] = sum_k A[m][(k%KA)]*B[n][k] ----
// SINGLE-BUFFERED (round-10 form): stage -> barrier -> ds_read+MFMA -> barrier.
// Round-11 lesson: glds double-buffering makes the compiler emit a
// conservative vmcnt(0) before the ds_reads (it can't disambiguate in-flight
// LDS writes), serializing worse than the barrier drain. Overlap must come
// from TLP (block count), not intra-block pipelining.
// T1 XCD-chunked bijective swizzle; T2 k-slot XOR swizzle (both-sides, rule
// #21): logical slot l of row r at physical l ^ ((r>>1)&3); glds source
// pre-permuted by the same involution. Conflicts measured 0 (r10).
// BMAJ=1: B rows gathered from in-place dT via per-branch inverse time maps.
// NTW: n-tile width (128 / 64 / 32). Smaller NTW -> more blocks -> more TLP.
template <int KDIM, int KA, int MODE, int MT, int NBLK, int BMAJ = 0, int NTW = 128>
__global__ __launch_bounds__(256) void k_gemm_bt(const unsigned short* __restrict__ A,
                                                 const unsigned short* __restrict__ B,
                                                 float* __restrict__ O0f,
                                                 unsigned short* __restrict__ O0h,
                                                 unsigned short* __restrict__ O1h) {
  __shared__ unsigned short As[128 * 32];
  __shared__ unsigned short Bs[NTW * 32];
  constexpr int Q = NBLK / 8, R = NBLK % 8;
  constexpr int NFR = NTW / 32;  // n-frags per wave (128->4, 64->2, 32->1)
  int xcd = blockIdx.x & 7;
  int slot = blockIdx.x >> 3;
  int start = xcd * Q + (xcd < R ? xcd : R);
  int j = start + slot;
  int m0 = (j % MT) * 128;
  int n0 = (j / MT) * NTW;
  int tid = threadIdx.x;
  int lane = tid & 63;
  int wm = (tid >> 6) & 1;
  int wn = tid >> 7;
  int srow = tid >> 2;
  // source k-slot permuted by the LDS swizzle involution (row = tid>>2)
  int skof = (((tid & 3) ^ ((tid >> 3) & 3)) * 8);
  int brow0 = n0 + srow;       if (brow0 >= NBL) brow0 = NBL - 1;
  int brow1 = n0 + srow + 64;  if (brow1 >= NBL) brow1 = NBL - 1;  // NTW==128 only
  size_t rb0a = 0, rb0b = 0, rb0c = 0, rb1a = 0, rb1b = 0, rb1c = 0;
  if (BMAJ) {
    int bb0 = brow0 >= L_SEQ ? 1 : 0, l0 = brow0 - bb0 * L_SEQ;
    int t1_0 = L_SEQ - 1 - l0;
    int t2_0 = 5 * (l0 % 800) + l0 / 800;
    rb0a = ((size_t)(0 + bb0) * L_SEQ + l0) * DI;
    rb0b = ((size_t)(2 + bb0) * L_SEQ + t1_0) * DI;
    rb0c = ((size_t)(4 + bb0) * L_SEQ + t2_0) * DI;
    if (NTW == 128) {
      int bb1 = brow1 >= L_SEQ ? 1 : 0, l1 = brow1 - bb1 * L_SEQ;
      int t1_1 = L_SEQ - 1 - l1;
      int t2_1 = 5 * (l1 % 800) + l1 / 800;
      rb1a = ((size_t)(0 + bb1) * L_SEQ + l1) * DI;
      rb1b = ((size_t)(2 + bb1) * L_SEQ + t1_1) * DI;
      rb1c = ((size_t)(4 + bb1) * L_SEQ + t2_1) * DI;
    }
  }
  floatx4 zero = {0.f, 0.f, 0.f, 0.f};
  floatx4 acc[4][NFR];
#pragma unroll
  for (int i = 0; i < 4; ++i)
#pragma unroll
    for (int j2 = 0; j2 < NFR; ++j2) acc[i][j2] = zero;
  int ar = wm * 64 + (lane & 15);
  int br = wn * (NTW / 2) + (lane & 15);
  // fragment read: logical slot lane>>4 at physical slot ^((row>>1)&3);
  // (row>>1)&3 == (lane>>1)&3 for all row bases used here (multiples of 16).
  int kq = (((lane >> 4) ^ ((lane >> 1) & 3)) * 8);
  int brnk = 0, dd0 = 0;  // incremental k0/DI, k0%DI (BMAJ path)
  for (int k0 = 0; k0 < KDIM; k0 += 32) {
    int ka = (k0 % KA);
    glds16(&A[(size_t)(m0 + srow) * KA + ka + skof],      &As[tid * 8]);
    glds16(&A[(size_t)(m0 + srow + 64) * KA + ka + skof], &As[tid * 8 + 2048]);
    if (NTW >= 64 || tid < NTW * 4) {  // B staged by NTW*4 threads
      if (BMAJ) {
        size_t b0 = brnk == 0 ? rb0a : (brnk == 1 ? rb0b : rb0c);
        glds16(&B[b0 + dd0 + skof], &Bs[tid * 8]);
        if (NTW == 128) {
          size_t b1 = brnk == 0 ? rb1a : (brnk == 1 ? rb1b : rb1c);
          glds16(&B[b1 + dd0 + skof], &Bs[tid * 8 + 2048]);
        }
      } else {
        glds16(&B[(size_t)brow0 * KDIM + k0 + skof], &Bs[tid * 8]);
        if (NTW == 128)
          glds16(&B[(size_t)brow1 * KDIM + k0 + skof], &Bs[tid * 8 + 2048]);
      }
    }
    if (BMAJ) {
      dd0 += 32;
      if (dd0 == DI) { dd0 = 0; ++brnk; }
    }
    __syncthreads();
    short8 a[4], b[NFR];
#pragma unroll
    for (int i = 0; i < 4; ++i) a[i] = *(const short8*)&As[(ar + i * 16) * 32 + kq];
#pragma unroll
    for (int i = 0; i < NFR; ++i) b[i] = *(const short8*)&Bs[(br + i * 16) * 32 + kq];
#pragma unroll
    for (int mt = 0; mt < 4; ++mt)
#pragma unroll
      for (int nt = 0; nt < NFR; ++nt)
        acc[mt][nt] = __builtin_amdgcn_mfma_f32_16x16x32_bf16(a[mt], b[nt], acc[mt][nt], 0, 0, 0);
    __syncthreads();
  }
  int mq = m0 + wm * 64 + ((lane >> 4) << 2);
  int nq = n0 + wn * (NTW / 2) + (lane & 15);
#pragma unroll
  for (int nt = 0; nt < NFR; ++nt) {
    int n = nq + nt * 16;
    if (n >= NBL) continue;
#pragma unroll
    for (int mt = 0; mt < 4; ++mt) {
      int m = mq + mt * 16;
      floatx4 v = acc[mt][nt];
      if (MODE == 0) {
        *(floatx4*)&O0f[(size_t)n * DM + m] = v;
      } else {
        if (m < DI) {
          ushort4v r;
          r[0] = f2bf(v[0]); r[1] = f2bf(v[1]); r[2] = f2bf(v[2]); r[3] = f2bf(v[3]);
          *(ushort4v*)&O0h[(size_t)n * DI + m] = r;
        } else {
          ushort4v r;
          r[0] = f2bf(silu_f(v[0])); r[1] = f2bf(silu_f(v[1]));
          r[2] = f2bf(silu_f(v[2])); r[3] = f2bf(silu_f(v[3]));
          *(ushort4v*)&O1h[(size_t)n * DI + m - DI] = r;
        }
      }
    }
  }
}

// ---------------- conv+silu materialization: xTB[b][l][d] -> xaB[z][t][d] bf16 ----------------
__global__ __launch_bounds__(256) void k_conv_all(const unsigned short* __restrict__ xTB,
                                                  const float* __restrict__ cw_all,
                                                  unsigned short* __restrict__ xaB) {
  int z = blockIdx.z;
  int brn = z >> 1, b = z & 1;
  int d = blockIdx.x * 256 + threadIdx.x;
  int t0 = blockIdx.y * 8;
  const unsigned short* xrow = xTB + (size_t)b * L_SEQ * DI;
  float4 w = *(const float4*)&cw_all[((size_t)brn * DI + d) * 4];
  float xm3 = (t0 >= 3) ? bf2f(xrow[(size_t)map_t(brn, t0 - 3) * DI + d]) : 0.f;
  float xm2 = (t0 >= 2) ? bf2f(xrow[(size_t)map_t(brn, t0 - 2) * DI + d]) : 0.f;
  float xm1 = (t0 >= 1) ? bf2f(xrow[(size_t)map_t(brn, t0 - 1) * DI + d]) : 0.f;
#pragma unroll
  for (int i = 0; i < 8; ++i) {
    int t = t0 + i;
    float xc = bf2f(xrow[(size_t)map_t(brn, t) * DI + d]);
    float xa = silu_f(fmaf(w.w, xc, fmaf(w.z, xm1, fmaf(w.y, xm2, w.x * xm3))));
    xaB[((size_t)z * L_SEQ + t) * DI + d] = f2bf(xa);
    xm3 = xm2; xm2 = xm1; xm1 = xc;
  }
}

// ---------------- xproj MFMA: C[j][t] = sum_d xpw[j][d]*xa[z][t][d] ----------------
// Same T2 k-slot XOR swizzle as k_gemm_bt.
__global__ __launch_bounds__(256) void k_xprojm(const unsigned short* __restrict__ xpwB,
                                                const unsigned short* __restrict__ xaB,
                                                unsigned short* __restrict__ dtrB,
                                                float* __restrict__ BC) {
  __shared__ unsigned short As[128 * 32];
  __shared__ unsigned short Bs[128 * 32];
  int z = blockIdx.z;
  int brn = z >> 1;
  int n0 = blockIdx.x * 128;
  int tid = threadIdx.x;
  int lane = tid & 63;
  int wm = (tid >> 6) & 1;
  int wn = tid >> 7;
  int srow = tid >> 2;
  int skof = (((tid & 3) ^ ((tid >> 3) & 3)) * 8);
  int arow0 = srow;       if (arow0 > 79) arow0 = 79;
  int arow1 = srow + 64;  if (arow1 > 79) arow1 = 79;
  int brow0 = n0 + srow;       if (brow0 >= L_SEQ) brow0 = L_SEQ - 1;
  int brow1 = n0 + srow + 64;  if (brow1 >= L_SEQ) brow1 = L_SEQ - 1;
  const unsigned short* A = xpwB + (size_t)brn * 80 * DI;
  const unsigned short* Bm = xaB + (size_t)z * L_SEQ * DI;
  floatx4 zero = {0.f, 0.f, 0.f, 0.f};
  floatx4 acc[4][4];
#pragma unroll
  for (int i = 0; i < 4; ++i)
#pragma unroll
    for (int j = 0; j < 4; ++j) acc[i][j] = zero;
  int ar = wm * 64 + (lane & 15);
  int br = wn * 64 + (lane & 15);
  int kq = (((lane >> 4) ^ ((lane >> 1) & 3)) * 8);
  for (int k0 = 0; k0 < DI; k0 += 32) {
    glds16(&A[(size_t)arow0 * DI + k0 + skof], &As[tid * 8]);
    glds16(&A[(size_t)arow1 * DI + k0 + skof], &As[tid * 8 + 2048]);
    glds16(&Bm[(size_t)brow0 * DI + k0 + skof], &Bs[tid * 8]);
    glds16(&Bm[(size_t)brow1 * DI + k0 + skof], &Bs[tid * 8 + 2048]);
    __syncthreads();
    short8 a[4], b[4];
#pragma unroll
    for (int i = 0; i < 4; ++i) a[i] = *(const short8*)&As[(ar + i * 16) * 32 + kq];
#pragma unroll
    for (int i = 0; i < 4; ++i) b[i] = *(const short8*)&Bs[(br + i * 16) * 32 + kq];
#pragma unroll
    for (int mt = 0; mt < 4; ++mt)
#pragma unroll
      for (int nt = 0; nt < 4; ++nt)
        acc[mt][nt] = __builtin_amdgcn_mfma_f32_16x16x32_bf16(a[mt], b[nt], acc[mt][nt], 0, 0, 0);
    __syncthreads();
  }
  int mq = wm * 64 + ((lane >> 4) << 2);
  int nq = n0 + wn * 64 + (lane & 15);
#pragma unroll
  for (int nt = 0; nt < 4; ++nt) {
    int t = nq + nt * 16;
    if (t >= L_SEQ) continue;
#pragma unroll
    for (int mt = 0; mt < 4; ++mt) {
      int j = mq + mt * 16;
      if (j >= 80) continue;
      floatx4 v = acc[mt][nt];
      if (j < 48) {
        ushort4v r;
        r[0] = f2bf(v[0]); r[1] = f2bf(v[1]); r[2] = f2bf(v[2]); r[3] = f2bf(v[3]);
        *(ushort4v*)&dtrB[((size_t)z * L_SEQ + t) * DTRK + j] = r;
      } else {
#pragma unroll
        for (int r = 0; r < 4; ++r)
          BC[((size_t)z * 32 + (j + r - 48)) * L_SEQ + t] = v[r];
      }
    }
  }
}

// ---------------- delta GEMM (MFMA, K=48 padded to 64) + softplus -> bf16 [z][t][d]
// LDS layout XOR-swizzled: row of 64 shorts = 8 slots of 8 shorts; data for
// slot s of row r lives at slot s^(r&7). Fixes 16-way read / 32-way write
// bank conflicts of the linear 128-B-stride layout.
__global__ __launch_bounds__(256) void k_dtg(const unsigned short* __restrict__ dpwB,
                                             const unsigned short* __restrict__ dtrB,
                                             const float* __restrict__ dbias,
                                             unsigned short* __restrict__ dT) {
  __shared__ unsigned short As[128 * 64];
  __shared__ unsigned short Bs[128 * 64];
  int z = blockIdx.z;
  int brn = z >> 1;
  int m0 = blockIdx.y * 128;
  int n0 = blockIdx.x * 128;
  int tid = threadIdx.x;
  int lane = tid & 63;
  int wm = (tid >> 6) & 1;
  int wn = tid >> 7;
  {
    int zr = tid >> 1, zs = 6 + (tid & 1);
    ushort8 zz = {0, 0, 0, 0, 0, 0, 0, 0};
    *(ushort8*)&As[zr * 64 + ((zs ^ (zr & 7)) << 3)] = zz;
    *(ushort8*)&Bs[zr * 64 + ((zs ^ (zr & 7)) << 3)] = zz;
  }
  {
    int row = tid >> 1;
    int p0 = (tid & 1) * 3;
    const unsigned short* Ag = dpwB + (size_t)brn * DI * DTRK + (size_t)(m0 + row) * DTRK;
    int bro = n0 + row; if (bro > L_SEQ - 1) bro = L_SEQ - 1;
    const unsigned short* Bg = dtrB + ((size_t)z * L_SEQ + bro) * DTRK;
#pragma unroll
    for (int i = 0; i < 3; ++i) {
      int slot = p0 + i;
      int off = (slot ^ (row & 7)) << 3;
      *(ushort8*)&As[row * 64 + off] = *(const ushort8*)&Ag[slot << 3];
      *(ushort8*)&Bs[row * 64 + off] = *(const ushort8*)&Bg[slot << 3];
    }
  }
  __syncthreads();
  int ar = wm * 64 + (lane & 15);
  int brr = wn * 64 + (lane & 15);
  int kslot = lane >> 4;  // 0..3
  floatx4 zero = {0.f, 0.f, 0.f, 0.f};
  floatx4 acc[4][4];
#pragma unroll
  for (int i = 0; i < 4; ++i)
#pragma unroll
    for (int j = 0; j < 4; ++j) acc[i][j] = zero;
#pragma unroll
  for (int kk = 0; kk < 2; ++kk) {
    short8 a[4], b[4];
    int slot = kk * 4 + kslot;
#pragma unroll
    for (int i = 0; i < 4; ++i) {
      int r = ar + i * 16;
      a[i] = *(const short8*)&As[r * 64 + ((slot ^ (r & 7)) << 3)];
    }
#pragma unroll
    for (int i = 0; i < 4; ++i) {
      int r = brr + i * 16;
      b[i] = *(const short8*)&Bs[r * 64 + ((slot ^ (r & 7)) << 3)];
    }
#pragma unroll
    for (int mt = 0; mt < 4; ++mt)
#pragma unroll
      for (int nt = 0; nt < 4; ++nt)
        acc[mt][nt] = __builtin_amdgcn_mfma_f32_16x16x32_bf16(a[mt], b[nt], acc[mt][nt], 0, 0, 0);
  }
  int mq = m0 + wm * 64 + ((lane >> 4) << 2);
  int nq = n0 + wn * 64 + (lane & 15);
  float4 bi[4];
#pragma unroll
  for (int mt = 0; mt < 4; ++mt)
    bi[mt] = *(const float4*)&dbias[(size_t)brn * DI + mq + mt * 16];
#pragma unroll
  for (int nt = 0; nt < 4; ++nt) {
    int n = nq + nt * 16;
    if (n >= L_SEQ) continue;
#pragma unroll
    for (int mt = 0; mt < 4; ++mt) {
      int m = mq + mt * 16;
      floatx4 v = acc[mt][nt];
      ushort4v r;
      r[0] = f2bf(softplus_f(v[0] + bi[mt].x));
      r[1] = f2bf(softplus_f(v[1] + bi[mt].y));
      r[2] = f2bf(softplus_f(v[2] + bi[mt].z));
      r[3] = f2bf(softplus_f(v[3] + bi[mt].w));
      *(ushort4v*)&dT[((size_t)z * L_SEQ + n) * DI + m] = r;
    }
  }
}

__device__ __forceinline__ void load_a2(const float* __restrict__ A_log, int brn, int d,
                                        float* a2, bool& fastp) {
  fastp = true;
#pragma unroll
  for (int g = 0; g < 4; ++g) {
    float4 v = *(const float4*)&A_log[((size_t)brn * DI + d) * DS + g * 4];
    float av0 = __expf(v.x), av1 = __expf(v.y), av2 = __expf(v.z), av3 = __expf(v.w);
    a2[g * 4 + 0] = -av0 * 1.44269504f; a2[g * 4 + 1] = -av1 * 1.44269504f;
    a2[g * 4 + 2] = -av2 * 1.44269504f; a2[g * 4 + 3] = -av3 * 1.44269504f;
    fastp = fastp && fabsf(av0 - (float)(g * 4 + 1)) < 1e-3f
                  && fabsf(av1 - (float)(g * 4 + 2)) < 1e-3f
                  && fabsf(av2 - (float)(g * 4 + 3)) < 1e-3f
                  && fabsf(av3 - (float)(g * 4 + 4)) < 1e-3f;
  }
}

// ---------------- scan phase 1: per-chunk local state + delta-sum ----------------
// raw-bf16 pipeline slots: loads issue with NO attached conversion; bf2f happens
// only at the consuming body, 3 bodies later -> counted vmcnt, ~12 loads in flight.
#define S1_BODY(T, XV, DLV)                                                       \
  do {                                                                            \
    S += (DLV);                                                                   \
    float dtx_ = (DLV) * (XV);                                                    \
    float2v dc2[8];                                                               \
    if (fastp) {                                                                  \
      pow_ladder2(exp2f(-(DLV) * 1.44269504f), dc2);                              \
    } else {                                                                      \
      _Pragma("unroll")                                                           \
      for (int i = 0; i < 8; ++i)                                                 \
        dc2[i] = (float2v){exp2f((DLV) * a2[2 * i]), exp2f((DLV) * a2[2 * i + 1])}; \
    }                                                                             \
    const float2v* B2 = (const float2v*)&BtS[(T)][0];                             \
    float2v dtx2 = {dtx_, dtx_};                                                  \
    _Pragma("unroll")                                                             \
    for (int i = 0; i < 8; ++i)                                                   \
      h2[i] = __builtin_elementwise_fma(h2[i], dc2[i], dtx2 * B2[i]);             \
  } while (0)

__global__ __launch_bounds__(256) void k_scan1c(const unsigned short* __restrict__ xaB,
                                                const unsigned short* __restrict__ dT,
                                                const float* __restrict__ BC,
                                                const float* __restrict__ A_log,
                                                float* __restrict__ hO,
                                                float* __restrict__ Sc) {
  __shared__ float BtS[LC][16];
  int z = blockIdx.z;
  int brn = z >> 1;
  int ch = blockIdx.y;
  int t0 = ch * LC;
  int d = blockIdx.x * 256 + threadIdx.x;
  int tid = threadIdx.x;
  for (int i = tid; i < 320; i += 256) {
    int row = i / 20;
    int c4 = (i % 20) * 4;
    float4 v = *(const float4*)&BC[((size_t)z * 32 + row) * L_SEQ + t0 + c4];
    BtS[c4 + 0][row] = v.x; BtS[c4 + 1][row] = v.y;
    BtS[c4 + 2][row] = v.z; BtS[c4 + 3][row] = v.w;
  }
  float a2[16]; bool fastp;
  load_a2(A_log, brn, d, a2, fastp);
  const unsigned short* xbp = xaB + ((size_t)z * L_SEQ + t0) * DI + d;
  const unsigned short* dbp = dT + ((size_t)z * L_SEQ + t0) * DI + d;
  float2v h2[8];
#pragma unroll
  for (int i = 0; i < 8; ++i) h2[i] = (float2v){0.f, 0.f};
  float S = 0.f;
  // preload 4 raw slots (tt = 0..3)
  unsigned short rx_a = xbp[0],      rd_a = dbp[0];
  unsigned short rx_b = xbp[DI],     rd_b = dbp[DI];
  unsigned short rx_c = xbp[2 * DI], rd_c = dbp[2 * DI];
  unsigned short rx_d = xbp[3 * DI], rd_d = dbp[3 * DI];
  __syncthreads();
  for (int t4 = 0; t4 < LC; t4 += 4) {
    { float xv = bf2f(rx_a), dv = bf2f(rd_a); S1_BODY(t4 + 0, xv, dv); }
    { int tc = (t4 + 4 < LC) ? t4 + 4 : LC - 1; rx_a = xbp[tc * DI]; rd_a = dbp[tc * DI]; }
    { float xv = bf2f(rx_b), dv = bf2f(rd_b); S1_BODY(t4 + 1, xv, dv); }
    { int tc = (t4 + 5 < LC) ? t4 + 5 : LC - 1; rx_b = xbp[tc * DI]; rd_b = dbp[tc * DI]; }
    { float xv = bf2f(rx_c), dv = bf2f(rd_c); S1_BODY(t4 + 2, xv, dv); }
    { int tc = (t4 + 6 < LC) ? t4 + 6 : LC - 1; rx_c = xbp[tc * DI]; rd_c = dbp[tc * DI]; }
    { float xv = bf2f(rx_d), dv = bf2f(rd_d); S1_BODY(t4 + 3, xv, dv); }
    { int tc = (t4 + 7 < LC) ? t4 + 7 : LC - 1; rx_d = xbp[tc * DI]; rd_d = dbp[tc * DI]; }
  }
  size_t base = (((size_t)z * NCH + ch) * DI + d) * 16;
#pragma unroll
  for (int i = 0; i < 8; ++i) *(float2v*)&hO[base + i * 2] = h2[i];
  Sc[((size_t)z * NCH + ch) * DI + d] = S;
}

// ---------------- scan phase 2: sequential combine over chunks (depth-4 prefetch) ----------------
__global__ __launch_bounds__(256) void k_scan2c(float* __restrict__ hO,
                                                const float* __restrict__ Sc,
                                                const float* __restrict__ A_log) {
  int idx = blockIdx.x * 256 + threadIdx.x;
  int z = idx / (DI * 16);
  int rem = idx % (DI * 16);
  int brn = z >> 1;
  float a2 = -__expf(A_log[(size_t)brn * DI * DS + rem]) * 1.44269504f;
  const int HS = DI * 16;
  size_t p = (size_t)z * NCH * HS + rem;
  size_t q = (size_t)z * NCH * DI + (rem >> 4);
  float th_a = hO[p];            float s_a = Sc[q];
  float th_b = hO[p + HS];       float s_b = Sc[q + DI];
  float th_c = hO[p + 2 * HS];   float s_c = Sc[q + 2 * DI];
  float th_d = hO[p + 3 * HS];   float s_d = Sc[q + 3 * DI];
  float H = 0.f;
  for (int c4 = 0; c4 < 48; c4 += 4) {
    hO[p] = H; H = fmaf(exp2f(s_a * a2), H, th_a);
    th_a = hO[p + 4 * HS]; s_a = Sc[q + 4 * DI];        // c4+4 <= 48 always
    p += HS; q += DI;
    hO[p] = H; H = fmaf(exp2f(s_b * a2), H, th_b);
    th_b = hO[p + 4 * HS]; s_b = Sc[q + 4 * DI];        // c4+5 <= 49 always
    p += HS; q += DI;
    hO[p] = H; H = fmaf(exp2f(s_c * a2), H, th_c);
    if (c4 + 6 < NCH) { th_c = hO[p + 4 * HS]; s_c = Sc[q + 4 * DI]; }
    p += HS; q += DI;
    hO[p] = H; H = fmaf(exp2f(s_d * a2), H, th_d);
    if (c4 + 7 < NCH) { th_d = hO[p + 4 * HS]; s_d = Sc[q + 4 * DI]; }
    p += HS; q += DI;
  }
  // tail: c = 48, 49
  hO[p] = H; H = fmaf(exp2f(s_a * a2), H, th_a); p += HS;
  hO[p] = H;
}

// ---------------- scan phase 3: reads xaB + dT, writes y*sz IN PLACE into dT ----
// Each dT element (z,t,d) is consumed by exactly one thread at exactly one body,
// then overwritten by that same thread (read runs 4 steps ahead of the write)
// -> no inter-thread hazard, no ybuf. The branch-time->output-position
// permutation is resolved by the out-proj GEMM's B-row gather (BMAJ=1).
#define S3D(T, XV, DLV, SZV)                                                      \
  do {                                                                            \
    float dtx_ = (DLV) * (XV);                                                    \
    float2v dc2[8];                                                               \
    if (fastp) {                                                                  \
      pow_ladder2(exp2f(-(DLV) * 1.44269504f), dc2);                              \
    } else {                                                                      \
      _Pragma("unroll")                                                           \
      for (int i = 0; i < 8; ++i)                                                 \
        dc2[i] = (float2v){exp2f((DLV) * a2[2 * i]), exp2f((DLV) * a2[2 * i + 1])}; \
    }                                                                             \
    const float2v* B2 = (const float2v*)&BCt[(T)][0];                             \
    const float2v* C2 = (const float2v*)&BCt[(T)][16];                            \
    float2v dtx2 = {dtx_, dtx_};                                                  \
    float2v y2a = {0.f, 0.f}, y2b = {0.f, 0.f};                                   \
    _Pragma("unroll")                                                             \
    for (int i = 0; i < 4; ++i) {                                                 \
      h2[i] = __builtin_elementwise_fma(h2[i], dc2[i], dtx2 * B2[i]);             \
      y2a = __builtin_elementwise_fma(h2[i], C2[i], y2a);                         \
    }                                                                             \
    _Pragma("unroll")                                                             \
    for (int i = 4; i < 8; ++i) {                                                 \
      h2[i] = __builtin_elementwise_fma(h2[i], dc2[i], dtx2 * B2[i]);             \
      y2b = __builtin_elementwise_fma(h2[i], C2[i], y2b);                         \
    }                                                                             \
    float y_ = (y2a[0] + y2a[1]) + (y2b[0] + y2b[1]) + Dv * (XV);                 \
    dp[(size_t)(T) * DI] = f2bf(y_ * (SZV));                                      \
  } while (0)

__global__ __launch_bounds__(256) void k_scan3d(const unsigned short* __restrict__ xaB,
                                                unsigned short* __restrict__ dT,
                                                const float* __restrict__ BC,
                                                const float* __restrict__ A_log,
                                                const float* __restrict__ Dp,
                                                const float* __restrict__ hO,
                                                const unsigned short* __restrict__ szTB) {
  __shared__ float BCt[LC][32];
  int z = blockIdx.z;
  int brn = z >> 1, b = z & 1;
  int ch = blockIdx.y;
  int t0 = ch * LC;
  int d = blockIdx.x * 256 + threadIdx.x;
  int tid = threadIdx.x;
  for (int i = tid; i < 640; i += 256) {
    int row = i / 20;
    int c4 = (i % 20) * 4;
    float4 v = *(const float4*)&BC[((size_t)z * 32 + row) * L_SEQ + t0 + c4];
    BCt[c4 + 0][row] = v.x; BCt[c4 + 1][row] = v.y;
    BCt[c4 + 2][row] = v.z; BCt[c4 + 3][row] = v.w;
  }
  float a2[16]; bool fastp;
  load_a2(A_log, brn, d, a2, fastp);
  float Dv = Dp[(size_t)brn * DI + d];
  const unsigned short* xp = xaB + ((size_t)z * L_SEQ + t0) * DI + d;
  unsigned short* dp = dT + ((size_t)z * L_SEQ + t0) * DI + d;
  const unsigned short* szb = szTB + (size_t)b * L_SEQ * DI + d;
  float2v h2[8];
  size_t hbase = (((size_t)z * NCH + ch) * DI + d) * 16;
#pragma unroll
  for (int i = 0; i < 8; ++i) h2[i] = *(const float2v*)&hO[hbase + i * 2];
  // closed-form in-chunk row map (sz gather only; xa/del/store are sequential).
  bool isb2 = (brn == 2);
  int mbase = (brn == 1) ? (L_SEQ - 1 - t0) : t0;
  int msign = (brn == 1) ? -1 : 1;
  int chb = ch * 16;
  auto mrow = [&](int tt) -> int {
    if (isb2) return (tt % 5) * 800 + chb + tt / 5;
    return mbase + msign * tt;
  };
  // preload 4 raw slots (tt = 0..3)
  unsigned short rx_a = xp[0],      rl_a = dp[0],      rs_a = szb[(size_t)mrow(0) * DI];
  unsigned short rx_b = xp[DI],     rl_b = dp[DI],     rs_b = szb[(size_t)mrow(1) * DI];
  unsigned short rx_c = xp[2 * DI], rl_c = dp[2 * DI], rs_c = szb[(size_t)mrow(2) * DI];
  unsigned short rx_d = xp[3 * DI], rl_d = dp[3 * DI], rs_d = szb[(size_t)mrow(3) * DI];
  __syncthreads();
  for (int t4 = 0; t4 < LC; t4 += 4) {
    { float xv = bf2f(rx_a), dv = bf2f(rl_a), sv = bf2f(rs_a); S3D(t4 + 0, xv, dv, sv); }
    { int tc = (t4 + 4 < LC) ? t4 + 4 : LC - 1;
      rx_a = xp[(size_t)tc * DI]; rl_a = dp[(size_t)tc * DI]; rs_a = szb[(size_t)mrow(tc) * DI]; }
    { float xv = bf2f(rx_b), dv = bf2f(rl_b), sv = bf2f(rs_b); S3D(t4 + 1, xv, dv, sv); }
    { int tc = (t4 + 5 < LC) ? t4 + 5 : LC - 1;
      rx_b = xp[(size_t)tc * DI]; rl_b = dp[(size_t)tc * DI]; rs_b = szb[(size_t)mrow(tc) * DI]; }
    { float xv = bf2f(rx_c), dv = bf2f(rl_c), sv = bf2f(rs_c); S3D(t4 + 2, xv, dv, sv); }
    { int tc = (t4 + 6 < LC) ? t4 + 6 : LC - 1;
      rx_c = xp[(size_t)tc * DI]; rl_c = dp[(size_t)tc * DI]; rs_c = szb[(size_t)mrow(tc) * DI]; }
    { float xv = bf2f(rx_d), dv = bf2f(rl_d), sv = bf2f(rs_d); S3D(t4 + 3, xv, dv, sv); }
    { int tc = (t4 + 7 < LC) ? t4 + 7 : LC - 1;
      rx_d = xp[(size_t)tc * DI]; rl_d = dp[(size_t)tc * DI]; rs_d = szb[(size_t)mrow(tc) * DI]; }
  }
}

extern "C" void kernel_launch(void* const* d_in, const int* in_sizes, int n_in,
                              void* d_out, int out_size, void* d_ws, size_t ws_size,
                              hipStream_t stream) {
  const float* hs        = (const float*)d_in[0];
  const float* in_proj_w = (const float*)d_in[1];
  const float* conv_w    = (const float*)d_in[2];
  const float* x_proj_w  = (const float*)d_in[3];
  const float* dt_proj_w = (const float*)d_in[4];
  const float* dt_bias   = (const float*)d_in[5];
  const float* A_log     = (const float*)d_in[6];
  const float* D_param   = (const float*)d_in[7];
  const float* out_proj_w= (const float*)d_in[8];
  float* out = (float*)d_out;
  float* ws = (float*)d_ws;

  unsigned short* xTB  = (unsigned short*)(ws);             // 12,288,000 sh
  unsigned short* szTB = (unsigned short*)(ws + 6144000);   // 12,288,000 sh
  unsigned short* dtrB = (unsigned short*)(ws + 12288000);  // 1,152,000 sh
  float* BC            = ws + 12864000;                     // 768,000 f
  unsigned short* dT   = (unsigned short*)(ws + 13632000);  // 36,864,000 sh (delta, then y in place)
  float* hO            = ws + 32064000;                     // 7,372,800 f
  float* Sc            = ws + 39436800;                     // 460,800 f
  unsigned short* dpwB = (unsigned short*)(ws + 39897600);  // 221,184 sh
  unsigned short* OWb  = (unsigned short*)(ws + 40008192);  // 1,179,648 sh
  // region R (disjoint lifetimes): {hsB, Wb} -> {xaB}; xaB stays live through scan3d
  unsigned short* hsB  = (unsigned short*)(ws + 40598016);  // 6,144,000 sh
  unsigned short* Wb   = hsB + 6144000;                     // 2,359,296 sh
  unsigned short* xaB  = (unsigned short*)(ws + 40598016);  // 36,864,000 sh
  unsigned short* xpwB = (unsigned short*)(ws + 59030016);  // 368,640 sh

  k_cast5<<<5016, 256, 0, stream>>>(hs, hsB, in_proj_w, Wb, out_proj_w, OWb,
                                    dt_proj_w, dpwB, x_proj_w, xpwB);

  // in-proj: 24 m-tiles x 63 n-tiles = 1512 blocks, XCD-chunked n-major swizzle
  k_gemm_bt<DM, DM, 1, 24, 1512><<<1512, 256, 0, stream>>>(Wb, hsB, nullptr, xTB, szTB);

  k_conv_all<<<dim3(6, 500, 6), 256, 0, stream>>>(xTB, conv_w, xaB);
  k_xprojm<<<dim3(32, 1, 6), 256, 0, stream>>>(xpwB, xaB, dtrB, BC);
  k_dtg<<<dim3(32, 12, 6), 256, 0, stream>>>(dpwB, dtrB, dt_bias, dT);

  k_scan1c<<<dim3(6, NCH, 6), 256, 0, stream>>>(xaB, dT, BC, A_log, hO, Sc);
  k_scan2c<<<576, 256, 0, stream>>>(hO, Sc, A_log);
  // scan3: reads xaB (kept live), writes y*sz in place into dT
  k_scan3d<<<dim3(6, NCH, 6), 256, 0, stream>>>(xaB, dT, BC, A_log, D_param, hO, szTB);

  // out-proj: B = dT branch-major gather (BMAJ=1), 32-wide n-tiles:
  // 6 m-tiles x 250 n-tiles = 1500 blocks (~6/CU, ~24 waves) for TLP-based
  // latency hiding (r11 showed intra-block glds pipelining is compiler-defeated)
  k_gemm_bt<3 * DI, DI, 0, 6, 1500, 1, 32><<<1500, 256, 0, stream>>>(OWb, dT, out, nullptr, nullptr);
}

// Round 13
// 509.457 us; speedup vs baseline: 1.3389x; 1.1389x over previous
//
#include <hip/hip_runtime.h>
#include <math.h>

#define L_SEQ 4000
#define DM 768
#define DI 1536
#define DS 16
#define DTRK 48
#define NCH 50
#define LC 80
#define NBL 8000

typedef __attribute__((ext_vector_type(8))) short short8;
typedef __attribute__((ext_vector_type(8))) unsigned short ushort8;
typedef __attribute__((ext_vector_type(4))) unsigned short ushort4v;
typedef __attribute__((ext_vector_type(4))) float floatx4;
typedef __attribute__((ext_vector_type(2))) float float2v;

__device__ __forceinline__ float silu_f(float x) { return x / (1.f + __expf(-x)); }
// fast softplus: log1pf -> __logf(1+e); e>0 so no cancellation; when 1+e rounds
// to 1 the true value <= 6e-8, invisible in bf16 output.
__device__ __forceinline__ float softplus_f(float x) {
  return fmaxf(x, 0.f) + __logf(1.f + __expf(-fabsf(x)));
}
__device__ __forceinline__ int map_t(int branch, int t) {
  if (branch == 0) return t;
  if (branch == 1) return L_SEQ - 1 - t;
  return (t % 5) * 800 + t / 5;
}
__device__ __forceinline__ unsigned short f2bf(float f) {
  unsigned int u = __float_as_uint(f);
  u = (u + 0x7fffu + ((u >> 16) & 1u)) >> 16;
  return (unsigned short)u;
}
__device__ __forceinline__ float bf2f(unsigned short u) {
  return __uint_as_float(((unsigned int)u) << 16);
}
__device__ __forceinline__ void glds16(const void* g, void* l) {
  __builtin_amdgcn_global_load_lds((const __attribute__((address_space(1))) void*)g,
                                   (__attribute__((address_space(3))) void*)l, 16, 0, 0);
}
// packed power ladder, TREE form (dep depth 4 vs 8 of the serial ladder):
// dc2[i] = {E^(2i+1), E^(2i+2)} for i=0..7, built from E2/E4/E8 squarings.
__device__ __forceinline__ void pow_ladder2(float E1, float2v* dc2) {
  float E2 = E1 * E1;
  float E4 = E2 * E2;
  float E8 = E4 * E4;
  float2v v4 = {E4, E4}, v8 = {E8, E8};
  dc2[0] = (float2v){E1, E2};
  dc2[1] = dc2[0] * (float2v){E2, E2};  // E3,E4
  dc2[2] = dc2[0] * v4;                 // E5,E6
  dc2[3] = dc2[1] * v4;                 // E7,E8
  dc2[4] = dc2[0] * v8;                 // E9,E10
  dc2[5] = dc2[1] * v8;                 // E11,E12
  dc2[6] = dc2[2] * v8;                 // E13,E14
  dc2[7] = dc2[3] * v8;                 // E15,E16
}

// ---------------- merged cast fp32 -> bf16 for all 5 weight/input arrays ----------------
__device__ __forceinline__ void cast_seg(const float* __restrict__ src,
                                         unsigned short* __restrict__ dst,
                                         int blk, int n) {
  int i = (blk * 256 + (int)threadIdx.x) * 8;
  if (i >= n) return;
  float4 v0 = *(const float4*)&src[i];
  float4 v1 = *(const float4*)&src[i + 4];
  ushort8 r;
  r[0] = f2bf(v0.x); r[1] = f2bf(v0.y); r[2] = f2bf(v0.z); r[3] = f2bf(v0.w);
  r[4] = f2bf(v1.x); r[5] = f2bf(v1.y); r[6] = f2bf(v1.z); r[7] = f2bf(v1.w);
  *(ushort8*)&dst[i] = r;
}
__global__ __launch_bounds__(256) void k_cast5(const float* s0, unsigned short* d0,
                                               const float* s1, unsigned short* d1,
                                               const float* s2, unsigned short* d2,
                                               const float* s3, unsigned short* d3,
                                               const float* s4, unsigned short* d4) {
  int blk = blockIdx.x;
  if (blk < 3000)      cast_seg(s0, d0, blk,        6144000);
  else if (blk < 4152) cast_seg(s1, d1, blk - 3000, 2359296);
  else if (blk < 4728) cast_seg(s2, d2, blk - 4152, 1179648);
  else if (blk < 4836) cast_seg(s3, d3, blk - 4728, 221184);
  else                 cast_seg(s4, d4, blk - 4836, 368640);
}

// ---------------- MFMA GEMM (bt): C[m][n] = sum_k A[m][(k%KA)]*B[n][k] ----
// Round-10 phase structure (stage -> ONE barrier/drain -> ds_read+MFMA ->
// barrier) widened to K-step 64: BOTH 32-wide sub-tiles staged into separate
// LDS buffers in the SAME phase, halving barrier-pair count (r12 showed the
// cost scales with iteration count, not TLP). NOT r11's cross-phase dbuf:
// all staging completes before the single drain, so the compiler's
// conservative vmcnt adds nothing.
// T1 XCD-chunked bijective swizzle; T2 k-slot XOR swizzle (both-sides, rule
// #21): logical slot l of row r at physical l ^ ((r>>1)&3); glds source
// pre-permuted by the same involution. Conflicts measured 0 (r10).
// BMAJ=1: B rows gathered from in-place dT via per-branch inverse time maps
// (sub-tiles never cross a branch: DI%64==0).
template <int KDIM, int KA, int MODE, int MT, int NBLK, int BMAJ = 0, int NTW = 128>
__global__ __launch_bounds__(256) void k_gemm_bt(const unsigned short* __restrict__ A,
                                                 const unsigned short* __restrict__ B,
                                                 float* __restrict__ O0f,
                                                 unsigned short* __restrict__ O0h,
                                                 unsigned short* __restrict__ O1h) {
  __shared__ unsigned short As[2][128 * 32];
  __shared__ unsigned short Bs[2][NTW * 32];
  constexpr int Q = NBLK / 8, R = NBLK % 8;
  constexpr int NFR = NTW / 32;  // n-frags per wave (128->4, 64->2)
  int xcd = blockIdx.x & 7;
  int slot = blockIdx.x >> 3;
  int start = xcd * Q + (xcd < R ? xcd : R);
  int j = start + slot;
  int m0 = (j % MT) * 128;
  int n0 = (j / MT) * NTW;
  int tid = threadIdx.x;
  int lane = tid & 63;
  int wm = (tid >> 6) & 1;
  int wn = tid >> 7;
  int srow = tid >> 2;
  // source k-slot permuted by the LDS swizzle involution (row = tid>>2)
  int skof = (((tid & 3) ^ ((tid >> 3) & 3)) * 8);
  int brow0 = n0 + srow;       if (brow0 >= NBL) brow0 = NBL - 1;
  int brow1 = n0 + srow + 64;  if (brow1 >= NBL) brow1 = NBL - 1;  // NTW==128 only
  size_t rb0a = 0, rb0b = 0, rb0c = 0, rb1a = 0, rb1b = 0, rb1c = 0;
  if (BMAJ) {
    int bb0 = brow0 >= L_SEQ ? 1 : 0, l0 = brow0 - bb0 * L_SEQ;
    int t1_0 = L_SEQ - 1 - l0;
    int t2_0 = 5 * (l0 % 800) + l0 / 800;
    rb0a = ((size_t)(0 + bb0) * L_SEQ + l0) * DI;
    rb0b = ((size_t)(2 + bb0) * L_SEQ + t1_0) * DI;
    rb0c = ((size_t)(4 + bb0) * L_SEQ + t2_0) * DI;
    if (NTW == 128) {
      int bb1 = brow1 >= L_SEQ ? 1 : 0, l1 = brow1 - bb1 * L_SEQ;
      int t1_1 = L_SEQ - 1 - l1;
      int t2_1 = 5 * (l1 % 800) + l1 / 800;
      rb1a = ((size_t)(0 + bb1) * L_SEQ + l1) * DI;
      rb1b = ((size_t)(2 + bb1) * L_SEQ + t1_1) * DI;
      rb1c = ((size_t)(4 + bb1) * L_SEQ + t2_1) * DI;
    }
  }
  floatx4 zero = {0.f, 0.f, 0.f, 0.f};
  floatx4 acc[4][NFR];
#pragma unroll
  for (int i = 0; i < 4; ++i)
#pragma unroll
    for (int j2 = 0; j2 < NFR; ++j2) acc[i][j2] = zero;
  int ar = wm * 64 + (lane & 15);
  int br = wn * (NTW / 2) + (lane & 15);
  // fragment read: logical slot lane>>4 at physical slot ^((row>>1)&3);
  // (row>>1)&3 == (lane>>1)&3 for all row bases used here (multiples of 16).
  int kq = (((lane >> 4) ^ ((lane >> 1) & 3)) * 8);
  int brnk = 0, dd0 = 0;  // incremental k0/DI, k0%DI (BMAJ path)
  for (int k0 = 0; k0 < KDIM; k0 += 64) {
#pragma unroll
    for (int h = 0; h < 2; ++h) {
      int kh = k0 + h * 32;
      int ka = (kh % KA);
      glds16(&A[(size_t)(m0 + srow) * KA + ka + skof],      &As[h][tid * 8]);
      glds16(&A[(size_t)(m0 + srow + 64) * KA + ka + skof], &As[h][tid * 8 + 2048]);
      if (BMAJ) {
        int ddh = dd0 + h * 32;
        size_t b0 = brnk == 0 ? rb0a : (brnk == 1 ? rb0b : rb0c);
        glds16(&B[b0 + ddh + skof], &Bs[h][tid * 8]);
        if (NTW == 128) {
          size_t b1 = brnk == 0 ? rb1a : (brnk == 1 ? rb1b : rb1c);
          glds16(&B[b1 + ddh + skof], &Bs[h][tid * 8 + 2048]);
        }
      } else {
        glds16(&B[(size_t)brow0 * KDIM + kh + skof], &Bs[h][tid * 8]);
        if (NTW == 128)
          glds16(&B[(size_t)brow1 * KDIM + kh + skof], &Bs[h][tid * 8 + 2048]);
      }
    }
    if (BMAJ) {
      dd0 += 64;
      if (dd0 == DI) { dd0 = 0; ++brnk; }
    }
    __syncthreads();
#pragma unroll
    for (int h = 0; h < 2; ++h) {
      short8 a[4], b[NFR];
#pragma unroll
      for (int i = 0; i < 4; ++i) a[i] = *(const short8*)&As[h][(ar + i * 16) * 32 + kq];
#pragma unroll
      for (int i = 0; i < NFR; ++i) b[i] = *(const short8*)&Bs[h][(br + i * 16) * 32 + kq];
#pragma unroll
      for (int mt = 0; mt < 4; ++mt)
#pragma unroll
        for (int nt = 0; nt < NFR; ++nt)
          acc[mt][nt] = __builtin_amdgcn_mfma_f32_16x16x32_bf16(a[mt], b[nt], acc[mt][nt], 0, 0, 0);
    }
    __syncthreads();
  }
  int mq = m0 + wm * 64 + ((lane >> 4) << 2);
  int nq = n0 + wn * (NTW / 2) + (lane & 15);
#pragma unroll
  for (int nt = 0; nt < NFR; ++nt) {
    int n = nq + nt * 16;
    if (n >= NBL) continue;
#pragma unroll
    for (int mt = 0; mt < 4; ++mt) {
      int m = mq + mt * 16;
      floatx4 v = acc[mt][nt];
      if (MODE == 0) {
        *(floatx4*)&O0f[(size_t)n * DM + m] = v;
      } else {
        if (m < DI) {
          ushort4v r;
          r[0] = f2bf(v[0]); r[1] = f2bf(v[1]); r[2] = f2bf(v[2]); r[3] = f2bf(v[3]);
          *(ushort4v*)&O0h[(size_t)n * DI + m] = r;
        } else {
          ushort4v r;
          r[0] = f2bf(silu_f(v[0])); r[1] = f2bf(silu_f(v[1]));
          r[2] = f2bf(silu_f(v[2])); r[3] = f2bf(silu_f(v[3]));
          *(ushort4v*)&O1h[(size_t)n * DI + m - DI] = r;
        }
      }
    }
  }
}

// ---------------- conv+silu materialization: xTB[b][l][d] -> xaB[z][t][d] bf16 ----------------
__global__ __launch_bounds__(256) void k_conv_all(const unsigned short* __restrict__ xTB,
                                                  const float* __restrict__ cw_all,
                                                  unsigned short* __restrict__ xaB) {
  int z = blockIdx.z;
  int brn = z >> 1, b = z & 1;
  int d = blockIdx.x * 256 + threadIdx.x;
  int t0 = blockIdx.y * 8;
  const unsigned short* xrow = xTB + (size_t)b * L_SEQ * DI;
  float4 w = *(const float4*)&cw_all[((size_t)brn * DI + d) * 4];
  float xm3 = (t0 >= 3) ? bf2f(xrow[(size_t)map_t(brn, t0 - 3) * DI + d]) : 0.f;
  float xm2 = (t0 >= 2) ? bf2f(xrow[(size_t)map_t(brn, t0 - 2) * DI + d]) : 0.f;
  float xm1 = (t0 >= 1) ? bf2f(xrow[(size_t)map_t(brn, t0 - 1) * DI + d]) : 0.f;
#pragma unroll
  for (int i = 0; i < 8; ++i) {
    int t = t0 + i;
    float xc = bf2f(xrow[(size_t)map_t(brn, t) * DI + d]);
    float xa = silu_f(fmaf(w.w, xc, fmaf(w.z, xm1, fmaf(w.y, xm2, w.x * xm3))));
    xaB[((size_t)z * L_SEQ + t) * DI + d] = f2bf(xa);
    xm3 = xm2; xm2 = xm1; xm1 = xc;
  }
}

// ---------------- xproj MFMA: C[j][t] = sum_d xpw[j][d]*xa[z][t][d] ----------------
// Same T2 k-slot XOR swizzle as k_gemm_bt.
__global__ __launch_bounds__(256) void k_xprojm(const unsigned short* __restrict__ xpwB,
                                                const unsigned short* __restrict__ xaB,
                                                unsigned short* __restrict__ dtrB,
                                                float* __restrict__ BC) {
  __shared__ unsigned short As[128 * 32];
  __shared__ unsigned short Bs[128 * 32];
  int z = blockIdx.z;
  int brn = z >> 1;
  int n0 = blockIdx.x * 128;
  int tid = threadIdx.x;
  int lane = tid & 63;
  int wm = (tid >> 6) & 1;
  int wn = tid >> 7;
  int srow = tid >> 2;
  int skof = (((tid & 3) ^ ((tid >> 3) & 3)) * 8);
  int arow0 = srow;       if (arow0 > 79) arow0 = 79;
  int arow1 = srow + 64;  if (arow1 > 79) arow1 = 79;
  int brow0 = n0 + srow;       if (brow0 >= L_SEQ) brow0 = L_SEQ - 1;
  int brow1 = n0 + srow + 64;  if (brow1 >= L_SEQ) brow1 = L_SEQ - 1;
  const unsigned short* A = xpwB + (size_t)brn * 80 * DI;
  const unsigned short* Bm = xaB + (size_t)z * L_SEQ * DI;
  floatx4 zero = {0.f, 0.f, 0.f, 0.f};
  floatx4 acc[4][4];
#pragma unroll
  for (int i = 0; i < 4; ++i)
#pragma unroll
    for (int j = 0; j < 4; ++j) acc[i][j] = zero;
  int ar = wm * 64 + (lane & 15);
  int br = wn * 64 + (lane & 15);
  int kq = (((lane >> 4) ^ ((lane >> 1) & 3)) * 8);
  for (int k0 = 0; k0 < DI; k0 += 32) {
    glds16(&A[(size_t)arow0 * DI + k0 + skof], &As[tid * 8]);
    glds16(&A[(size_t)arow1 * DI + k0 + skof], &As[tid * 8 + 2048]);
    glds16(&Bm[(size_t)brow0 * DI + k0 + skof], &Bs[tid * 8]);
    glds16(&Bm[(size_t)brow1 * DI + k0 + skof], &Bs[tid * 8 + 2048]);
    __syncthreads();
    short8 a[4], b[4];
#pragma unroll
    for (int i = 0; i < 4; ++i) a[i] = *(const short8*)&As[(ar + i * 16) * 32 + kq];
#pragma unroll
    for (int i = 0; i < 4; ++i) b[i] = *(const short8*)&Bs[(br + i * 16) * 32 + kq];
#pragma unroll
    for (int mt = 0; mt < 4; ++mt)
#pragma unroll
      for (int nt = 0; nt < 4; ++nt)
        acc[mt][nt] = __builtin_amdgcn_mfma_f32_16x16x32_bf16(a[mt], b[nt], acc[mt][nt], 0, 0, 0);
    __syncthreads();
  }
  int mq = wm * 64 + ((lane >> 4) << 2);
  int nq = n0 + wn * 64 + (lane & 15);
#pragma unroll
  for (int nt = 0; nt < 4; ++nt) {
    int t = nq + nt * 16;
    if (t >= L_SEQ) continue;
#pragma unroll
    for (int mt = 0; mt < 4; ++mt) {
      int j = mq + mt * 16;
      if (j >= 80) continue;
      floatx4 v = acc[mt][nt];
      if (j < 48) {
        ushort4v r;
        r[0] = f2bf(v[0]); r[1] = f2bf(v[1]); r[2] = f2bf(v[2]); r[3] = f2bf(v[3]);
        *(ushort4v*)&dtrB[((size_t)z * L_SEQ + t) * DTRK + j] = r;
      } else {
#pragma unroll
        for (int r = 0; r < 4; ++r)
          BC[((size_t)z * 32 + (j + r - 48)) * L_SEQ + t] = v[r];
      }
    }
  }
}

// ---------------- delta GEMM (MFMA, K=48 padded to 64) + softplus -> bf16 [z][t][d]
// LDS layout XOR-swizzled: row of 64 shorts = 8 slots of 8 shorts; data for
// slot s of row r lives at slot s^(r&7). Fixes 16-way read / 32-way write
// bank conflicts of the linear 128-B-stride layout.
__global__ __launch_bounds__(256) void k_dtg(const unsigned short* __restrict__ dpwB,
                                             const unsigned short* __restrict__ dtrB,
                                             const float* __restrict__ dbias,
                                             unsigned short* __restrict__ dT) {
  __shared__ unsigned short As[128 * 64];
  __shared__ unsigned short Bs[128 * 64];
  int z = blockIdx.z;
  int brn = z >> 1;
  int m0 = blockIdx.y * 128;
  int n0 = blockIdx.x * 128;
  int tid = threadIdx.x;
  int lane = tid & 63;
  int wm = (tid >> 6) & 1;
  int wn = tid >> 7;
  {
    int zr = tid >> 1, zs = 6 + (tid & 1);
    ushort8 zz = {0, 0, 0, 0, 0, 0, 0, 0};
    *(ushort8*)&As[zr * 64 + ((zs ^ (zr & 7)) << 3)] = zz;
    *(ushort8*)&Bs[zr * 64 + ((zs ^ (zr & 7)) << 3)] = zz;
  }
  {
    int row = tid >> 1;
    int p0 = (tid & 1) * 3;
    const unsigned short* Ag = dpwB + (size_t)brn * DI * DTRK + (size_t)(m0 + row) * DTRK;
    int bro = n0 + row; if (bro > L_SEQ - 1) bro = L_SEQ - 1;
    const unsigned short* Bg = dtrB + ((size_t)z * L_SEQ + bro) * DTRK;
#pragma unroll
    for (int i = 0; i < 3; ++i) {
      int slot = p0 + i;
      int off = (slot ^ (row & 7)) << 3;
      *(ushort8*)&As[row * 64 + off] = *(const ushort8*)&Ag[slot << 3];
      *(ushort8*)&Bs[row * 64 + off] = *(const ushort8*)&Bg[slot << 3];
    }
  }
  __syncthreads();
  int ar = wm * 64 + (lane & 15);
  int brr = wn * 64 + (lane & 15);
  int kslot = lane >> 4;  // 0..3
  floatx4 zero = {0.f, 0.f, 0.f, 0.f};
  floatx4 acc[4][4];
#pragma unroll
  for (int i = 0; i < 4; ++i)
#pragma unroll
    for (int j = 0; j < 4; ++j) acc[i][j] = zero;
#pragma unroll
  for (int kk = 0; kk < 2; ++kk) {
    short8 a[4], b[4];
    int slot = kk * 4 + kslot;
#pragma unroll
    for (int i = 0; i < 4; ++i) {
      int r = ar + i * 16;
      a[i] = *(const short8*)&As[r * 64 + ((slot ^ (r & 7)) << 3)];
    }
#pragma unroll
    for (int i = 0; i < 4; ++i) {
      int r = brr + i * 16;
      b[i] = *(const short8*)&Bs[r * 64 + ((slot ^ (r & 7)) << 3)];
    }
#pragma unroll
    for (int mt = 0; mt < 4; ++mt)
#pragma unroll
      for (int nt = 0; nt < 4; ++nt)
        acc[mt][nt] = __builtin_amdgcn_mfma_f32_16x16x32_bf16(a[mt], b[nt], acc[mt][nt], 0, 0, 0);
  }
  int mq = m0 + wm * 64 + ((lane >> 4) << 2);
  int nq = n0 + wn * 64 + (lane & 15);
  float4 bi[4];
#pragma unroll
  for (int mt = 0; mt < 4; ++mt)
    bi[mt] = *(const float4*)&dbias[(size_t)brn * DI + mq + mt * 16];
#pragma unroll
  for (int nt = 0; nt < 4; ++nt) {
    int n = nq + nt * 16;
    if (n >= L_SEQ) continue;
#pragma unroll
    for (int mt = 0; mt < 4; ++mt) {
      int m = mq + mt * 16;
      floatx4 v = acc[mt][nt];
      ushort4v r;
      r[0] = f2bf(softplus_f(v[0] + bi[mt].x));
      r[1] = f2bf(softplus_f(v[1] + bi[mt].y));
      r[2] = f2bf(softplus_f(v[2] + bi[mt].z));
      r[3] = f2bf(softplus_f(v[3] + bi[mt].w));
      *(ushort4v*)&dT[((size_t)z * L_SEQ + n) * DI + m] = r;
    }
  }
}

__device__ __forceinline__ void load_a2(const float* __restrict__ A_log, int brn, int d,
                                        float* a2, bool& fastp) {
  fastp = true;
#pragma unroll
  for (int g = 0; g < 4; ++g) {
    float4 v = *(const float4*)&A_log[((size_t)brn * DI + d) * DS + g * 4];
    float av0 = __expf(v.x), av1 = __expf(v.y), av2 = __expf(v.z), av3 = __expf(v.w);
    a2[g * 4 + 0] = -av0 * 1.44269504f; a2[g * 4 + 1] = -av1 * 1.44269504f;
    a2[g * 4 + 2] = -av2 * 1.44269504f; a2[g * 4 + 3] = -av3 * 1.44269504f;
    fastp = fastp && fabsf(av0 - (float)(g * 4 + 1)) < 1e-3f
                  && fabsf(av1 - (float)(g * 4 + 2)) < 1e-3f
                  && fabsf(av2 - (float)(g * 4 + 3)) < 1e-3f
                  && fabsf(av3 - (float)(g * 4 + 4)) < 1e-3f;
  }
}

// ---------------- scan phase 1: per-chunk local state + delta-sum ----------------
// raw-bf16 pipeline slots: loads issue with NO attached conversion; bf2f happens
// only at the consuming body, 3 bodies later -> counted vmcnt, ~12 loads in flight.
#define S1_BODY(T, XV, DLV)                                                       \
  do {                                                                            \
    S += (DLV);                                                                   \
    float dtx_ = (DLV) * (XV);                                                    \
    float2v dc2[8];                                                               \
    if (fastp) {                                                                  \
      pow_ladder2(exp2f(-(DLV) * 1.44269504f), dc2);                              \
    } else {                                                                      \
      _Pragma("unroll")                                                           \
      for (int i = 0; i < 8; ++i)                                                 \
        dc2[i] = (float2v){exp2f((DLV) * a2[2 * i]), exp2f((DLV) * a2[2 * i + 1])}; \
    }                                                                             \
    const float2v* B2 = (const float2v*)&BtS[(T)][0];                             \
    float2v dtx2 = {dtx_, dtx_};                                                  \
    _Pragma("unroll")                                                             \
    for (int i = 0; i < 8; ++i)                                                   \
      h2[i] = __builtin_elementwise_fma(h2[i], dc2[i], dtx2 * B2[i]);             \
  } while (0)

__global__ __launch_bounds__(256) void k_scan1c(const unsigned short* __restrict__ xaB,
                                                const unsigned short* __restrict__ dT,
                                                const float* __restrict__ BC,
                                                const float* __restrict__ A_log,
                                                float* __restrict__ hO,
                                                float* __restrict__ Sc) {
  __shared__ float BtS[LC][16];
  int z = blockIdx.z;
  int brn = z >> 1;
  int ch = blockIdx.y;
  int t0 = ch * LC;
  int d = blockIdx.x * 256 + threadIdx.x;
  int tid = threadIdx.x;
  for (int i = tid; i < 320; i += 256) {
    int row = i / 20;
    int c4 = (i % 20) * 4;
    float4 v = *(const float4*)&BC[((size_t)z * 32 + row) * L_SEQ + t0 + c4];
    BtS[c4 + 0][row] = v.x; BtS[c4 + 1][row] = v.y;
    BtS[c4 + 2][row] = v.z; BtS[c4 + 3][row] = v.w;
  }
  float a2[16]; bool fastp;
  load_a2(A_log, brn, d, a2, fastp);
  const unsigned short* xbp = xaB + ((size_t)z * L_SEQ + t0) * DI + d;
  const unsigned short* dbp = dT + ((size_t)z * L_SEQ + t0) * DI + d;
  float2v h2[8];
#pragma unroll
  for (int i = 0; i < 8; ++i) h2[i] = (float2v){0.f, 0.f};
  float S = 0.f;
  // preload 4 raw slots (tt = 0..3)
  unsigned short rx_a = xbp[0],      rd_a = dbp[0];
  unsigned short rx_b = xbp[DI],     rd_b = dbp[DI];
  unsigned short rx_c = xbp[2 * DI], rd_c = dbp[2 * DI];
  unsigned short rx_d = xbp[3 * DI], rd_d = dbp[3 * DI];
  __syncthreads();
  for (int t4 = 0; t4 < LC; t4 += 4) {
    { float xv = bf2f(rx_a), dv = bf2f(rd_a); S1_BODY(t4 + 0, xv, dv); }
    { int tc = (t4 + 4 < LC) ? t4 + 4 : LC - 1; rx_a = xbp[tc * DI]; rd_a = dbp[tc * DI]; }
    { float xv = bf2f(rx_b), dv = bf2f(rd_b); S1_BODY(t4 + 1, xv, dv); }
    { int tc = (t4 + 5 < LC) ? t4 + 5 : LC - 1; rx_b = xbp[tc * DI]; rd_b = dbp[tc * DI]; }
    { float xv = bf2f(rx_c), dv = bf2f(rd_c); S1_BODY(t4 + 2, xv, dv); }
    { int tc = (t4 + 6 < LC) ? t4 + 6 : LC - 1; rx_c = xbp[tc * DI]; rd_c = dbp[tc * DI]; }
    { float xv = bf2f(rx_d), dv = bf2f(rd_d); S1_BODY(t4 + 3, xv, dv); }
    { int tc = (t4 + 7 < LC) ? t4 + 7 : LC - 1; rx_d = xbp[tc * DI]; rd_d = dbp[tc * DI]; }
  }
  size_t base = (((size_t)z * NCH + ch) * DI + d) * 16;
#pragma unroll
  for (int i = 0; i < 8; ++i) *(float2v*)&hO[base + i * 2] = h2[i];
  Sc[((size_t)z * NCH + ch) * DI + d] = S;
}

// ---------------- scan phase 2: sequential combine over chunks (depth-4 prefetch) ----------------
__global__ __launch_bounds__(256) void k_scan2c(float* __restrict__ hO,
                                                const float* __restrict__ Sc,
                                                const float* __restrict__ A_log) {
  int idx = blockIdx.x * 256 + threadIdx.x;
  int z = idx / (DI * 16);
  int rem = idx % (DI * 16);
  int brn = z >> 1;
  float a2 = -__expf(A_log[(size_t)brn * DI * DS + rem]) * 1.44269504f;
  const int HS = DI * 16;
  size_t p = (size_t)z * NCH * HS + rem;
  size_t q = (size_t)z * NCH * DI + (rem >> 4);
  float th_a = hO[p];            float s_a = Sc[q];
  float th_b = hO[p + HS];       float s_b = Sc[q + DI];
  float th_c = hO[p + 2 * HS];   float s_c = Sc[q + 2 * DI];
  float th_d = hO[p + 3 * HS];   float s_d = Sc[q + 3 * DI];
  float H = 0.f;
  for (int c4 = 0; c4 < 48; c4 += 4) {
    hO[p] = H; H = fmaf(exp2f(s_a * a2), H, th_a);
    th_a = hO[p + 4 * HS]; s_a = Sc[q + 4 * DI];        // c4+4 <= 48 always
    p += HS; q += DI;
    hO[p] = H; H = fmaf(exp2f(s_b * a2), H, th_b);
    th_b = hO[p + 4 * HS]; s_b = Sc[q + 4 * DI];        // c4+5 <= 49 always
    p += HS; q += DI;
    hO[p] = H; H = fmaf(exp2f(s_c * a2), H, th_c);
    if (c4 + 6 < NCH) { th_c = hO[p + 4 * HS]; s_c = Sc[q + 4 * DI]; }
    p += HS; q += DI;
    hO[p] = H; H = fmaf(exp2f(s_d * a2), H, th_d);
    if (c4 + 7 < NCH) { th_d = hO[p + 4 * HS]; s_d = Sc[q + 4 * DI]; }
    p += HS; q += DI;
  }
  // tail: c = 48, 49
  hO[p] = H; H = fmaf(exp2f(s_a * a2), H, th_a); p += HS;
  hO[p] = H;
}

// ---------------- scan phase 3: reads xaB + dT, writes y*sz IN PLACE into dT ----
// Each dT element (z,t,d) is consumed by exactly one thread at exactly one body,
// then overwritten by that same thread (read runs 4 steps ahead of the write)
// -> no inter-thread hazard, no ybuf. The branch-time->output-position
// permutation is resolved by the out-proj GEMM's B-row gather (BMAJ=1).
#define S3D(T, XV, DLV, SZV)                                                      \
  do {                                                                            \
    float dtx_ = (DLV) * (XV);                                                    \
    float2v dc2[8];                                                               \
    if (fastp) {                                                                  \
      pow_ladder2(exp2f(-(DLV) * 1.44269504f), dc2);                              \
    } else {                                                                      \
      _Pragma("unroll")                                                           \
      for (int i = 0; i < 8; ++i)                                                 \
        dc2[i] = (float2v){exp2f((DLV) * a2[2 * i]), exp2f((DLV) * a2[2 * i + 1])}; \
    }                                                                             \
    const float2v* B2 = (const float2v*)&BCt[(T)][0];                             \
    const float2v* C2 = (const float2v*)&BCt[(T)][16];                            \
    float2v dtx2 = {dtx_, dtx_};                                                  \
    float2v y2a = {0.f, 0.f}, y2b = {0.f, 0.f};                                   \
    _Pragma("unroll")                                                             \
    for (int i = 0; i < 4; ++i) {                                                 \
      h2[i] = __builtin_elementwise_fma(h2[i], dc2[i], dtx2 * B2[i]);             \
      y2a = __builtin_elementwise_fma(h2[i], C2[i], y2a);                         \
    }                                                                             \
    _Pragma("unroll")                                                             \
    for (int i = 4; i < 8; ++i) {                                                 \
      h2[i] = __builtin_elementwise_fma(h2[i], dc2[i], dtx2 * B2[i]);             \
      y2b = __builtin_elementwise_fma(h2[i], C2[i], y2b);                         \
    }                                                                             \
    float y_ = (y2a[0] + y2a[1]) + (y2b[0] + y2b[1]) + Dv * (XV);                 \
    dp[(size_t)(T) * DI] = f2bf(y_ * (SZV));                                      \
  } while (0)

__global__ __launch_bounds__(256) void k_scan3d(const unsigned short* __restrict__ xaB,
                                                unsigned short* __restrict__ dT,
                                                const float* __restrict__ BC,
                                                const float* __restrict__ A_log,
                                                const float* __restrict__ Dp,
                                                const float* __restrict__ hO,
                                                const unsigned short* __restrict__ szTB) {
  __shared__ float BCt[LC][32];
  int z = blockIdx.z;
  int brn = z >> 1, b = z & 1;
  int ch = blockIdx.y;
  int t0 = ch * LC;
  int d = blockIdx.x * 256 + threadIdx.x;
  int tid = threadIdx.x;
  for (int i = tid; i < 640; i += 256) {
    int row = i / 20;
    int c4 = (i % 20) * 4;
    float4 v = *(const float4*)&BC[((size_t)z * 32 + row) * L_SEQ + t0 + c4];
    BCt[c4 + 0][row] = v.x; BCt[c4 + 1][row] = v.y;
    BCt[c4 + 2][row] = v.z; BCt[c4 + 3][row] = v.w;
  }
  float a2[16]; bool fastp;
  load_a2(A_log, brn, d, a2, fastp);
  float Dv = Dp[(size_t)brn * DI + d];
  const unsigned short* xp = xaB + ((size_t)z * L_SEQ + t0) * DI + d;
  unsigned short* dp = dT + ((size_t)z * L_SEQ + t0) * DI + d;
  const unsigned short* szb = szTB + (size_t)b * L_SEQ * DI + d;
  float2v h2[8];
  size_t hbase = (((size_t)z * NCH + ch) * DI + d) * 16;
#pragma unroll
  for (int i = 0; i < 8; ++i) h2[i] = *(const float2v*)&hO[hbase + i * 2];
  // closed-form in-chunk row map (sz gather only; xa/del/store are sequential).
  bool isb2 = (brn == 2);
  int mbase = (brn == 1) ? (L_SEQ - 1 - t0) : t0;
  int msign = (brn == 1) ? -1 : 1;
  int chb = ch * 16;
  auto mrow = [&](int tt) -> int {
    if (isb2) return (tt % 5) * 800 + chb + tt / 5;
    return mbase + msign * tt;
  };
  // preload 4 raw slots (tt = 0..3)
  unsigned short rx_a = xp[0],      rl_a = dp[0],      rs_a = szb[(size_t)mrow(0) * DI];
  unsigned short rx_b = xp[DI],     rl_b = dp[DI],     rs_b = szb[(size_t)mrow(1) * DI];
  unsigned short rx_c = xp[2 * DI], rl_c = dp[2 * DI], rs_c = szb[(size_t)mrow(2) * DI];
  unsigned short rx_d = xp[3 * DI], rl_d = dp[3 * DI], rs_d = szb[(size_t)mrow(3) * DI];
  __syncthreads();
  for (int t4 = 0; t4 < LC; t4 += 4) {
    { float xv = bf2f(rx_a), dv = bf2f(rl_a), sv = bf2f(rs_a); S3D(t4 + 0, xv, dv, sv); }
    { int tc = (t4 + 4 < LC) ? t4 + 4 : LC - 1;
      rx_a = xp[(size_t)tc * DI]; rl_a = dp[(size_t)tc * DI]; rs_a = szb[(size_t)mrow(tc) * DI]; }
    { float xv = bf2f(rx_b), dv = bf2f(rl_b), sv = bf2f(rs_b); S3D(t4 + 1, xv, dv, sv); }
    { int tc = (t4 + 5 < LC) ? t4 + 5 : LC - 1;
      rx_b = xp[(size_t)tc * DI]; rl_b = dp[(size_t)tc * DI]; rs_b = szb[(size_t)mrow(tc) * DI]; }
    { float xv = bf2f(rx_c), dv = bf2f(rl_c), sv = bf2f(rs_c); S3D(t4 + 2, xv, dv, sv); }
    { int tc = (t4 + 6 < LC) ? t4 + 6 : LC - 1;
      rx_c = xp[(size_t)tc * DI]; rl_c = dp[(size_t)tc * DI]; rs_c = szb[(size_t)mrow(tc) * DI]; }
    { float xv = bf2f(rx_d), dv = bf2f(rl_d), sv = bf2f(rs_d); S3D(t4 + 3, xv, dv, sv); }
    { int tc = (t4 + 7 < LC) ? t4 + 7 : LC - 1;
      rx_d = xp[(size_t)tc * DI]; rl_d = dp[(size_t)tc * DI]; rs_d = szb[(size_t)mrow(tc) * DI]; }
  }
}

extern "C" void kernel_launch(void* const* d_in, const int* in_sizes, int n_in,
                              void* d_out, int out_size, void* d_ws, size_t ws_size,
                              hipStream_t stream) {
  const float* hs        = (const float*)d_in[0];
  const float* in_proj_w = (const float*)d_in[1];
  const float* conv_w    = (const float*)d_in[2];
  const float* x_proj_w  = (const float*)d_in[3];
  const float* dt_proj_w = (const float*)d_in[4];
  const float* dt_bias   = (const float*)d_in[5];
  const float* A_log     = (const float*)d_in[6];
  const float* D_param   = (const float*)d_in[7];
  const float* out_proj_w= (const float*)d_in[8];
  float* out = (float*)d_out;
  float* ws = (float*)d_ws;

  unsigned short* xTB  = (unsigned short*)(ws);             // 12,288,000 sh
  unsigned short* szTB = (unsigned short*)(ws + 6144000);   // 12,288,000 sh
  unsigned short* dtrB = (unsigned short*)(ws + 12288000);  // 1,152,000 sh
  float* BC            = ws + 12864000;                     // 768,000 f
  unsigned short* dT   = (unsigned short*)(ws + 13632000);  // 36,864,000 sh (delta, then y in place)
  float* hO            = ws + 32064000;                     // 7,372,800 f
  float* Sc            = ws + 39436800;                     // 460,800 f
  unsigned short* dpwB = (unsigned short*)(ws + 39897600);  // 221,184 sh
  unsigned short* OWb  = (unsigned short*)(ws + 40008192);  // 1,179,648 sh
  // region R (disjoint lifetimes): {hsB, Wb} -> {xaB}; xaB stays live through scan3d
  unsigned short* hsB  = (unsigned short*)(ws + 40598016);  // 6,144,000 sh
  unsigned short* Wb   = hsB + 6144000;                     // 2,359,296 sh
  unsigned short* xaB  = (unsigned short*)(ws + 40598016);  // 36,864,000 sh
  unsigned short* xpwB = (unsigned short*)(ws + 59030016);  // 368,640 sh

  k_cast5<<<5016, 256, 0, stream>>>(hs, hsB, in_proj_w, Wb, out_proj_w, OWb,
                                    dt_proj_w, dpwB, x_proj_w, xpwB);

  // in-proj: 24 m-tiles x 63 n-tiles = 1512 blocks, XCD-chunked n-major swizzle,
  // K-step 64 (12 iters)
  k_gemm_bt<DM, DM, 1, 24, 1512><<<1512, 256, 0, stream>>>(Wb, hsB, nullptr, xTB, szTB);

  k_conv_all<<<dim3(6, 500, 6), 256, 0, stream>>>(xTB, conv_w, xaB);
  k_xprojm<<<dim3(32, 1, 6), 256, 0, stream>>>(xpwB, xaB, dtrB, BC);
  k_dtg<<<dim3(32, 12, 6), 256, 0, stream>>>(dpwB, dtrB, dt_bias, dT);

  k_scan1c<<<dim3(6, NCH, 6), 256, 0, stream>>>(xaB, dT, BC, A_log, hO, Sc);
  k_scan2c<<<576, 256, 0, stream>>>(hO, Sc, A_log);
  // scan3: reads xaB (kept live), writes y*sz in place into dT
  k_scan3d<<<dim3(6, NCH, 6), 256, 0, stream>>>(xaB, dT, BC, A_log, D_param, hO, szTB);

  // out-proj: B = dT branch-major gather (BMAJ=1), 64-wide n-tiles,
  // 750 blocks (TLP optimum per r9/r12), K-step 64 (72 iters vs 144)
  k_gemm_bt<3 * DI, DI, 0, 6, 750, 1, 64><<<750, 256, 0, stream>>>(OWb, dT, out, nullptr, nullptr);
}